// Round 18
// baseline (348.793 us; speedup 1.0000x reference)
//
#include <hip/hip_runtime.h>
#include <stdint.h>

#define AS1 __attribute__((address_space(1)))
#define AS3 __attribute__((address_space(3)))

using bf16x8 = __attribute__((ext_vector_type(8))) short;
using f32x4  = __attribute__((ext_vector_type(4))) float;

// ---- helpers -------------------------------------------------------------
__device__ __forceinline__ unsigned short f2bf(float f) {
  union { float f; unsigned u; } v; v.f = f;
  return (unsigned short)((v.u + 0x7FFFu + ((v.u >> 16) & 1u)) >> 16); // RNE
}
__device__ __forceinline__ float bf2f(unsigned short h) {
  union { unsigned u; float f; } v; v.u = ((unsigned)h) << 16;
  return v.f;
}
// async global->LDS, 16B per lane; lds dest must be wave-uniform base (HW adds lane*16)
__device__ __forceinline__ void gload_lds16(const void* g, void* l) {
  __builtin_amdgcn_global_load_lds((AS1 const void*)g, (AS3 void*)l, 16, 0, 0);
}

// ---- fused fp32 -> bf16 convert for x + 4 weights (one launch) ------------
__global__ void k_cvt5(const float* __restrict__ x,  const float* __restrict__ wq,
                       const float* __restrict__ wk, const float* __restrict__ wv,
                       const float* __restrict__ wo,
                       unsigned short* __restrict__ xb,  unsigned short* __restrict__ wqb,
                       unsigned short* __restrict__ wkb, unsigned short* __restrict__ wvb,
                       unsigned short* __restrict__ wob) {
  int idx = blockIdx.x * blockDim.x + threadIdx.x;
  int stride = gridDim.x * blockDim.x;
  for (int i = idx; i < 6291456; i += stride) {
    const float* src; unsigned short* dst; int off;
    if (i < 2097152) { src = x; dst = xb; off = i; }
    else {
      int j = i - 2097152;
      int w = j >> 20;            // 1,048,576 float4 per weight
      off = j & 1048575;
      src = (w == 0) ? wq : (w == 1) ? wk : (w == 2) ? wv : wo;
      dst = (w == 0) ? wqb : (w == 1) ? wkb : (w == 2) ? wvb : wob;
    }
    float4 f = ((const float4*)src)[off];
    ushort4 o;
    o.x = f2bf(f.x); o.y = f2bf(f.y); o.z = f2bf(f.z); o.w = f2bf(f.w);
    ((ushort4*)dst)[off] = o;
  }
}

// ---- RoPE tables: cos/sin[t][i], i in [0,64) ------------------------------
__global__ void k_rope_tables(float* __restrict__ ct, float* __restrict__ st) {
  int idx = blockIdx.x * blockDim.x + threadIdx.x;
  int t = idx >> 6, i = idx & 63;
  float invf = exp2f(-(float)i * (13.287712379549449f / 64.0f));
  float a = (float)t * invf;
  ct[idx] = cosf(a);
  st[idx] = sinf(a);
}

// ---- RoPE apply in-place on q and k [BH, T, 128] bf16 ---------------------
// q pre-scaled by (1/sqrt(128))*log2(e): flash logits are base-2.
__global__ void k_rope(unsigned short* __restrict__ q, unsigned short* __restrict__ k,
                       const float* __restrict__ ct, const float* __restrict__ st) {
  const float SC2 = 0.12751659974141322f;
  int idx = blockIdx.x * blockDim.x + threadIdx.x;
  int i = idx & 63;
  int t = (idx >> 6) & 2047;
  int bh = idx >> 17;
  size_t base = ((size_t)bh * 2048 + t) * 128;
  float c = ct[t * 64 + i], s = st[t * 64 + i];
  {
    float x1 = bf2f(q[base + i]), x2 = bf2f(q[base + i + 64]);
    q[base + i]      = f2bf((x1 * c - x2 * s) * SC2);
    q[base + i + 64] = f2bf((x2 * c + x1 * s) * SC2);
  }
  {
    float x1 = bf2f(k[base + i]), x2 = bf2f(k[base + i + 64]);
    k[base + i]      = f2bf(x1 * c - x2 * s);
    k[base + i + 64] = f2bf(x2 * c + x1 * s);
  }
}

// ---- 256x256 8-phase GEMM (m201 template; EXACT r10 form) -----------------
template <int MODE>
__global__ __launch_bounds__(512, 2) void k_gemm256(
    const unsigned short* __restrict__ Ag,
    const unsigned short* __restrict__ B0,
    const unsigned short* __restrict__ B1,
    const unsigned short* __restrict__ B2,
    float* __restrict__ outF,
    unsigned short* __restrict__ outQ,
    unsigned short* __restrict__ outK,
    unsigned short* __restrict__ outVT) {
  __shared__ __align__(16) unsigned short lds[65536]; // 128 KiB

  const int tid = threadIdx.x;
  const int wid = tid >> 6, lane = tid & 63;
  const int wm = wid >> 2, wn = wid & 3;
  const int rowA = lane & 15, kg = lane >> 4;
  const int rgrp = kg * 4;
  const int swz = rowA & 7;

  const int m0 = blockIdx.y * 256;
  const int n0g = blockIdx.x * 256;
  int w, n0;
  const unsigned short* Bg;
  if (MODE == 0) { w = 0; n0 = n0g; Bg = B0; }
  else { w = n0g >> 11; n0 = n0g & 2047; Bg = (w == 0) ? B0 : (w == 1) ? B1 : B2; }

  const int aBase = wm * 8192 + rowA * 64;
  const int bBase = (wn >> 1) * 8192 + ((wn & 1) * 64 + rowA) * 64;
  const int ch0 = (kg ^ swz) * 8;
  const int ch1 = ((4 + kg) ^ swz) * 8;

  const int grow = wid * 8 + (lane >> 3);
  const int gch  = ((lane & 7) ^ ((lane >> 3) & 7)) * 8;
  const int sdst = wid * 512;

  auto SA = [&](int dst, int t1, int h, int j) {
    gload_lds16(Ag + (size_t)(m0 + h * 128 + j * 64 + grow) * 2048 + t1 * 64 + gch,
                (void*)&lds[dst * 16384 + h * 8192 + j * 4096 + sdst]);
  };
  auto SB = [&](int dst, int t1, int h, int j) {
    gload_lds16(Bg + (size_t)(n0 + h * 128 + j * 64 + grow) * 2048 + t1 * 64 + gch,
                (void*)&lds[32768 + dst * 16384 + h * 8192 + j * 4096 + sdst]);
  };

  f32x4 acc[8][4];
  const f32x4 z4 = {0.f, 0.f, 0.f, 0.f};
#pragma unroll
  for (int i = 0; i < 8; ++i)
#pragma unroll
    for (int j = 0; j < 4; ++j) acc[i][j] = z4;

  SA(0, 0, 0, 0); SA(0, 0, 0, 1); SA(0, 0, 1, 0); SA(0, 0, 1, 1);
  SB(0, 0, 0, 0); SB(0, 0, 0, 1); SB(0, 0, 1, 0); SB(0, 0, 1, 1);
  __syncthreads();

  for (int t = 0; t < 32; ++t) {
    const int c = t & 1, d = c ^ 1;
    const int cA = c * 16384, cB = 32768 + c * 16384;
    const bool pre = (t + 1 < 32);
    const int t1 = t + 1;
    bf16x8 af[4], af2[4], bk[4];

#pragma unroll
    for (int i = 0; i < 4; ++i) af[i] = *(const bf16x8*)&lds[cA + aBase + i * 1024 + ch0];
#pragma unroll
    for (int j = 0; j < 4; ++j) bk[j] = *(const bf16x8*)&lds[cB + bBase + j * 1024 + ch0];
    if (pre) { SA(d, t1, 0, 0); SA(d, t1, 0, 1); }
    __builtin_amdgcn_s_barrier();
    __builtin_amdgcn_sched_barrier(0);
    __builtin_amdgcn_s_setprio(1);
#pragma unroll
    for (int i = 0; i < 4; ++i)
#pragma unroll
      for (int j = 0; j < 4; ++j)
        acc[i][j] = __builtin_amdgcn_mfma_f32_16x16x32_bf16(af[i], bk[j], acc[i][j], 0, 0, 0);
    __builtin_amdgcn_s_setprio(0);
    __builtin_amdgcn_s_barrier();
    __builtin_amdgcn_sched_barrier(0);

#pragma unroll
    for (int i = 0; i < 4; ++i) af2[i] = *(const bf16x8*)&lds[cA + aBase + (i + 4) * 1024 + ch0];
    if (pre) { SA(d, t1, 1, 0); SA(d, t1, 1, 1); }
    __builtin_amdgcn_s_barrier();
    __builtin_amdgcn_sched_barrier(0);
    __builtin_amdgcn_s_setprio(1);
#pragma unroll
    for (int i = 0; i < 4; ++i)
#pragma unroll
      for (int j = 0; j < 4; ++j)
        acc[i + 4][j] = __builtin_amdgcn_mfma_f32_16x16x32_bf16(af2[i], bk[j], acc[i + 4][j], 0, 0, 0);
    __builtin_amdgcn_s_setprio(0);
    __builtin_amdgcn_s_barrier();
    __builtin_amdgcn_sched_barrier(0);

#pragma unroll
    for (int i = 0; i < 4; ++i) af[i] = *(const bf16x8*)&lds[cA + aBase + i * 1024 + ch1];
#pragma unroll
    for (int j = 0; j < 4; ++j) bk[j] = *(const bf16x8*)&lds[cB + bBase + j * 1024 + ch1];
    if (pre) { SB(d, t1, 0, 0); SB(d, t1, 0, 1); }
    __builtin_amdgcn_s_barrier();
    __builtin_amdgcn_sched_barrier(0);
    __builtin_amdgcn_s_setprio(1);
#pragma unroll
    for (int i = 0; i < 4; ++i)
#pragma unroll
      for (int j = 0; j < 4; ++j)
        acc[i][j] = __builtin_amdgcn_mfma_f32_16x16x32_bf16(af[i], bk[j], acc[i][j], 0, 0, 0);
    __builtin_amdgcn_s_setprio(0);
    __builtin_amdgcn_s_barrier();
    __builtin_amdgcn_sched_barrier(0);

#pragma unroll
    for (int i = 0; i < 4; ++i) af2[i] = *(const bf16x8*)&lds[cA + aBase + (i + 4) * 1024 + ch1];
    if (pre) { SB(d, t1, 1, 0); SB(d, t1, 1, 1); }
    __builtin_amdgcn_s_barrier();
    __builtin_amdgcn_sched_barrier(0);
    __builtin_amdgcn_s_setprio(1);
#pragma unroll
    for (int i = 0; i < 4; ++i)
#pragma unroll
      for (int j = 0; j < 4; ++j)
        acc[i + 4][j] = __builtin_amdgcn_mfma_f32_16x16x32_bf16(af2[i], bk[j], acc[i + 4][j], 0, 0, 0);
    __builtin_amdgcn_s_setprio(0);
    __syncthreads();
  }

#pragma unroll
  for (int i = 0; i < 8; ++i) {
#pragma unroll
    for (int j = 0; j < 4; ++j) {
      const int gm0 = m0 + wm * 128 + i * 16 + rgrp;
      const int gn  = n0 + wn * 64 + j * 16 + rowA;
      if (MODE == 0) {
#pragma unroll
        for (int r = 0; r < 4; ++r)
          outF[(size_t)(gm0 + r) * 2048 + gn] = acc[i][j][r];
      } else if (w == 2) {
        int h = gn >> 7, dd = gn & 127;
        int b = gm0 >> 11, tt = gm0 & 2047;
        ushort4 pk;
        pk.x = f2bf(acc[i][j][0]); pk.y = f2bf(acc[i][j][1]);
        pk.z = f2bf(acc[i][j][2]); pk.w = f2bf(acc[i][j][3]);
        *(ushort4*)&outVT[(((size_t)(b * 16 + h)) * 128 + dd) * 2048 + tt] = pk;
      } else {
        unsigned short* C = w ? outK : outQ;
        int h = gn >> 7, dd = gn & 127;
        int b = gm0 >> 11, tt = gm0 & 2047;
#pragma unroll
        for (int r = 0; r < 4; ++r)
          C[(((size_t)(b * 16 + h)) * 2048 + tt + r) * 128 + dd] = f2bf(acc[i][j][r]);
      }
    }
  }
}

// ---- output-projection GEMM: f32 out [M,N] (m97 structure) ----------------
__global__ __launch_bounds__(256) void k_gemm_o(const unsigned short* __restrict__ A,
                                                const unsigned short* __restrict__ Bw,
                                                float* __restrict__ Cout,
                                                int M, int N, int K) {
  __shared__ __align__(16) unsigned short As[128 * 64];
  __shared__ __align__(16) unsigned short Bs[128 * 64];

  const int tid = threadIdx.x;
  const int wid = tid >> 6, lane = tid & 63;
  const int wm = wid >> 1, wn = wid & 1;
  const int m0 = blockIdx.y * 128, n0 = blockIdx.x * 128;
  const int rowA = lane & 15;
  const int kgrp = (lane >> 4) * 8;
  const int rgrp = (lane >> 4) * 4;
  const int srow = lane >> 3;
  const int scol = (lane & 7) * 8;

  f32x4 acc[4][4];
  const f32x4 z4 = {0.f, 0.f, 0.f, 0.f};
#pragma unroll
  for (int i = 0; i < 4; ++i)
#pragma unroll
    for (int j = 0; j < 4; ++j) acc[i][j] = z4;

  for (int k0 = 0; k0 < K; k0 += 64) {
    __syncthreads();
#pragma unroll
    for (int i = 0; i < 4; ++i) {
      int c = wid * 4 + i;
      const unsigned short* ga = A  + (size_t)(m0 + c * 8 + srow) * K + k0 + scol;
      gload_lds16(ga, (void*)&As[c * 512]);
      const unsigned short* gb = Bw + (size_t)(n0 + c * 8 + srow) * K + k0 + scol;
      gload_lds16(gb, (void*)&Bs[c * 512]);
    }
    __syncthreads();
#pragma unroll
    for (int kk = 0; kk < 64; kk += 32) {
      bf16x8 af[4], bfv[4];
#pragma unroll
      for (int i = 0; i < 4; ++i)
        af[i] = *(const bf16x8*)&As[(wm * 64 + i * 16 + rowA) * 64 + kk + kgrp];
#pragma unroll
      for (int j = 0; j < 4; ++j)
        bfv[j] = *(const bf16x8*)&Bs[(wn * 64 + j * 16 + rowA) * 64 + kk + kgrp];
#pragma unroll
      for (int i = 0; i < 4; ++i)
#pragma unroll
        for (int j = 0; j < 4; ++j)
          acc[i][j] = __builtin_amdgcn_mfma_f32_16x16x32_bf16(af[i], bfv[j], acc[i][j], 0, 0, 0);
    }
  }

#pragma unroll
  for (int i = 0; i < 4; ++i)
#pragma unroll
    for (int j = 0; j < 4; ++j)
#pragma unroll
      for (int r = 0; r < 4; ++r) {
        int gm = m0 + wm * 64 + i * 16 + rgrp + r;
        int gn = n0 + wn * 64 + j * 16 + rowA;
        Cout[(size_t)gm * N + gn] = acc[i][j][r];
      }
}

// ---- flash attention fwd: QBLK=64, 512 balanced blocks, 64KB, 2 blocks/CU -
// r17 fixed the LDS but the GRID was 256 = 1 block/CU — there was never a
// second block to co-schedule. Now: 512 blocks (32 bh x 16 pairs of 64-row
// q-tiles, pair (31-pp, pp) processed sequentially -> 17 KV-tile iterations
// for EVERY block, scheduling-independent). Each of 4 waves owns 16 q-rows
// (m-dim dropped everywhere -> VGPR ~150). LDS stays 64KB (K/V tiles are
// 128x128 regardless of QBLK; P overlay needs 8KB of K's dead 16KB).
// Iteration skeleton identical to r17 (3 gates, vmcnt(8)/vmcnt(0)).
__global__ __launch_bounds__(256) void k_flash(const unsigned short* __restrict__ q,
                                               const unsigned short* __restrict__ k,
                                               const unsigned short* __restrict__ vt,
                                               unsigned short* __restrict__ obt) {
  // ush: K[16384] @0 (P overlays [0,4096)) | V[16384] @16384   (= 64 KiB)
  __shared__ __align__(16) unsigned short lds[32768];

  const int tid = threadIdx.x;
  const int wid = tid >> 6, lane = tid & 63;
  const int rowA = lane & 15, kg = lane >> 4;
  const int kgrp = kg * 8, rgrp = kg * 4;

  const int bid = blockIdx.x;          // 0..511
  const int xcd = bid & 7;             // round-robin XCD dispatch (perf-only)
  const int r0  = bid >> 3;            // 0..63
  const int bh  = xcd * 4 + (r0 & 3);  // 4 heads per XCD chunk
  const int pp  = r0 >> 2;             // 0..15
  const int b = bh >> 4, h = bh & 15;

  const int jbs[2] = {31 - pp, pp};    // 64-row q-tiles; heavy segment first
  const int nt0 = (jbs[0] >> 1) + 1, nt1 = (jbs[1] >> 1) + 1; // 128-wide tiles
  const int total = nt0 + nt1;         // = 17 for every block

  const unsigned short* qh  = q  + (size_t)bh * 2048 * 128;
  const unsigned short* kh  = k  + (size_t)bh * 2048 * 128;
  const unsigned short* vth = vt + (size_t)bh * 128 * 2048;

  // staging: wave covers rows wid*32 + i*4 + (lane>>4), i=0..7; 16 lanes/row
  const int srow = wid * 32 + (lane >> 4);
  auto STAGE_K = [&](int kv0) {
#pragma unroll
    for (int i = 0; i < 8; ++i) {
      int row = srow + i * 4;
      int ch  = (lane & 15) ^ (row & 7);
      gload_lds16(kh + (size_t)(kv0 + row) * 128 + ch * 8,
                  (void*)&lds[wid * 4096 + i * 512]);
    }
  };
  auto STAGE_V = [&](int kv0) {
#pragma unroll
    for (int i = 0; i < 8; ++i) {
      int row = srow + i * 4;               // d-dim row
      int ch  = (lane & 15) ^ (row & 7);
      gload_lds16(vth + (size_t)row * 2048 + kv0 + ch * 8,
                  (void*)&lds[16384 + wid * 4096 + i * 512]);
    }
  };

  const f32x4 z4 = {0.f, 0.f, 0.f, 0.f};
  bf16x8 qf[4];
  f32x4 o[8];
  float mprev[4], lsum[4];
  int q0w = 0;

  int seg = 0, it = 0;
  STAGE_K(0);   // 8 oldest vmem ops
  STAGE_V(0);   // 8 newest

  for (int u = 0; u < total; ++u) {
    const int nt = (seg == 0) ? nt0 : nt1;
    const int kv0 = it * 128;

    // ---- top gate: K(u) complete everywhere; V(u) may still fly ----
    asm volatile("s_waitcnt vmcnt(8)" ::: "memory");
    __builtin_amdgcn_s_barrier();
    __builtin_amdgcn_sched_barrier(0);

    if (it == 0) {   // segment init: Q fragments + state reset
      q0w = jbs[seg] * 64 + wid * 16;
#pragma unroll
      for (int kq = 0; kq < 4; ++kq)
        qf[kq] = *(const bf16x8*)(qh + (size_t)(q0w + rowA) * 128 + kq * 32 + kgrp);
#pragma unroll
      for (int dn = 0; dn < 8; ++dn) o[dn] = z4;
#pragma unroll
      for (int r2 = 0; r2 < 4; ++r2) { mprev[r2] = -1e30f; lsum[r2] = 0.f; }
    }

    // ---- S = Q K^T over 128 kv (swizzled LDS) ----
    f32x4 s[8];
#pragma unroll
    for (int n = 0; n < 8; ++n) s[n] = z4;
    __builtin_amdgcn_s_setprio(1);
#pragma unroll
    for (int kq = 0; kq < 4; ++kq) {
#pragma unroll
      for (int n = 0; n < 8; ++n) {
        int row = n * 16 + rowA;
        int ch  = (kq * 4 + kg) ^ (row & 7);
        bf16x8 bkk = *(const bf16x8*)&lds[row * 128 + ch * 8];
        s[n] = __builtin_amdgcn_mfma_f32_16x16x32_bf16(qf[kq], bkk, s[n], 0, 0, 0);
      }
    }
    __builtin_amdgcn_s_setprio(0);

    // ---- mid gate: V(u) drained + K reads done -> P region free, V visible
    asm volatile("s_waitcnt vmcnt(0) lgkmcnt(0)" ::: "memory");
    __builtin_amdgcn_s_barrier();
    __builtin_amdgcn_sched_barrier(0);

    // ---- causal mask (only the diagonal tile) ----
    if (kv0 + 127 > q0w) {
#pragma unroll
      for (int n = 0; n < 8; ++n)
#pragma unroll
        for (int r2 = 0; r2 < 4; ++r2) {
          int qg = q0w + rgrp + r2;
          int kgl = kv0 + n * 16 + rowA;
          if (kgl > qg) s[n][r2] = -1e30f;
        }
    }

    // ---- online softmax (base-2), step-major trees, defer-max ----
    float tmax[4];
#pragma unroll
    for (int r2 = 0; r2 < 4; ++r2) {
      float t = s[0][r2];
#pragma unroll
      for (int n = 1; n < 8; ++n) t = fmaxf(t, s[n][r2]);
      tmax[r2] = t;
    }
#pragma unroll
    for (int stp = 1; stp <= 8; stp <<= 1)
#pragma unroll
      for (int r2 = 0; r2 < 4; ++r2)
        tmax[r2] = fmaxf(tmax[r2], __shfl_xor(tmax[r2], stp));

    bool ok = true;
#pragma unroll
    for (int r2 = 0; r2 < 4; ++r2) ok = ok && (tmax[r2] <= mprev[r2] + 8.0f);
    const bool skip = __all(ok ? 1 : 0);

    float mnew[4], psum[4];
#pragma unroll
    for (int r2 = 0; r2 < 4; ++r2) {
      mnew[r2] = skip ? mprev[r2] : fmaxf(mprev[r2], tmax[r2]);
      float ps = 0.f;
#pragma unroll
      for (int n = 0; n < 8; ++n) {
        float pv = exp2f(s[n][r2] - mnew[r2]);
        s[n][r2] = pv;
        ps += pv;
      }
      psum[r2] = ps;
    }
#pragma unroll
    for (int stp = 1; stp <= 8; stp <<= 1)
#pragma unroll
      for (int r2 = 0; r2 < 4; ++r2)
        psum[r2] += __shfl_xor(psum[r2], stp);

#pragma unroll
    for (int r2 = 0; r2 < 4; ++r2) {
      if (skip) {
        lsum[r2] += psum[r2];
      } else {
        float alpha = exp2f(mprev[r2] - mnew[r2]);
        lsum[r2] = lsum[r2] * alpha + psum[r2];
        mprev[r2] = mnew[r2];
#pragma unroll
        for (int dn = 0; dn < 8; ++dn) o[dn][r2] *= alpha;
      }
    }

    // ---- PV in two passes; P [16][64]/wave overlays Kbuf[0..4096 ush) ----
    unsigned short* Pw = &lds[wid * 1024];
    const unsigned short* Vb = &lds[16384];
#pragma unroll
    for (int pass = 0; pass < 2; ++pass) {
#pragma unroll
      for (int nl = 0; nl < 4; ++nl)
#pragma unroll
        for (int r2 = 0; r2 < 4; ++r2) {
          int row = rgrp + r2;
          int col = nl * 16 + rowA;
          Pw[row * 64 + (col ^ ((row & 7) << 3))] = f2bf(s[pass * 4 + nl][r2]);
        }
      // per-wave DS ordering: compiler inserts lgkmcnt waits before reads
      __builtin_amdgcn_s_setprio(1);
#pragma unroll
      for (int kkl = 0; kkl < 2; ++kkl) {
        const int kk = pass * 2 + kkl;
        bf16x8 pa;
        {
          int row = rowA;
          int col0 = kkl * 32 + kgrp;
          pa = *(const bf16x8*)&Pw[row * 64 + (col0 ^ ((row & 7) << 3))];
        }
#pragma unroll
        for (int dn = 0; dn < 8; ++dn) {
          int row = dn * 16 + rowA;
          int ch  = (kk * 4 + kg) ^ (row & 7);
          bf16x8 vb = *(const bf16x8*)&Vb[row * 128 + ch * 8];
          o[dn] = __builtin_amdgcn_mfma_f32_16x16x32_bf16(pa, vb, o[dn], 0, 0, 0);
        }
      }
      __builtin_amdgcn_s_setprio(0);
    }

    // ---- segment epilogue: normalize and write ----
    if (it == nt - 1) {
      float rinv[4];
#pragma unroll
      for (int r2 = 0; r2 < 4; ++r2) rinv[r2] = 1.0f / lsum[r2];
#pragma unroll
      for (int dn = 0; dn < 8; ++dn)
#pragma unroll
        for (int r2 = 0; r2 < 4; ++r2) {
          float v = o[dn][r2] * rinv[r2];
          int t = q0w + rgrp + r2;
          int col = h * 128 + dn * 16 + rowA;
          obt[((size_t)b * 2048 + t) * 2048 + col] = f2bf(v);
        }
    }

    __syncthreads(); // all P/V reads done; buffers reusable

    // ---- stage next K and V (K first = oldest; drained at next top gate) --
    if (u + 1 < total) {
      const int itn = (u + 1 >= nt0) ? (u + 1 - nt0) : (u + 1);
      STAGE_K(itn * 128);
      STAGE_V(itn * 128);
    }

    ++it;
    if (seg == 0 && it == nt0) { seg = 1; it = 0; }
  }
}

// ---- host launch -----------------------------------------------------------
extern "C" void kernel_launch(void* const* d_in, const int* in_sizes, int n_in,
                              void* d_out, int out_size, void* d_ws, size_t ws_size,
                              hipStream_t stream) {
  const float* x  = (const float*)d_in[0];
  const float* Wq = (const float*)d_in[2];
  const float* Wk = (const float*)d_in[3];
  const float* Wv = (const float*)d_in[4];
  const float* Wo = (const float*)d_in[5];
  float* out = (float*)d_out;

  char* ws = (char*)d_ws;
  unsigned short* xb  = (unsigned short*)(ws + 0);
  unsigned short* wqb = (unsigned short*)(ws + 16777216);
  unsigned short* wkb = (unsigned short*)(ws + 25165824);
  unsigned short* wvb = (unsigned short*)(ws + 33554432);
  unsigned short* wob = (unsigned short*)(ws + 41943040);
  unsigned short* qb  = (unsigned short*)(ws + 50331648);
  unsigned short* kb  = (unsigned short*)(ws + 67108864);
  unsigned short* vtb = (unsigned short*)(ws + 83886080);
  unsigned short* obt = (unsigned short*)(ws + 100663296);
  float* ct = (float*)(ws + 117440512);
  float* st = (float*)(ws + 117964800);

  k_cvt5<<<2048, 256, 0, stream>>>(x, Wq, Wk, Wv, Wo, xb, wqb, wkb, wvb, wob);
  k_rope_tables<<<512, 256, 0, stream>>>(ct, st);
  dim3 gq(24, 16); // merged QKV: 6144/256 x 4096/256, 512 thr
  k_gemm256<1><<<gq, 512, 0, stream>>>(xb, wqb, wkb, wvb, nullptr, qb, kb, vtb);
  k_rope<<<16384, 256, 0, stream>>>(qb, kb, ct, st);
  k_flash<<<512, 256, 0, stream>>>(qb, kb, vtb, obt);
  dim3 gg(16, 32);
  k_gemm_o<<<gg, 256, 0, stream>>>(obt, wob, out, 4096, 2048, 2048);
}

// Round 19
// 312.444 us; speedup vs baseline: 1.1163x; 1.1163x over previous
//
#include <hip/hip_runtime.h>
#include <stdint.h>

#define AS1 __attribute__((address_space(1)))
#define AS3 __attribute__((address_space(3)))

using bf16x8 = __attribute__((ext_vector_type(8))) short;
using f32x4  = __attribute__((ext_vector_type(4))) float;

// ---- helpers -------------------------------------------------------------
__device__ __forceinline__ unsigned short f2bf(float f) {
  union { float f; unsigned u; } v; v.f = f;
  return (unsigned short)((v.u + 0x7FFFu + ((v.u >> 16) & 1u)) >> 16); // RNE
}
__device__ __forceinline__ float bf2f(unsigned short h) {
  union { unsigned u; float f; } v; v.u = ((unsigned)h) << 16;
  return v.f;
}
// async global->LDS, 16B per lane; lds dest must be wave-uniform base (HW adds lane*16)
__device__ __forceinline__ void gload_lds16(const void* g, void* l) {
  __builtin_amdgcn_global_load_lds((AS1 const void*)g, (AS3 void*)l, 16, 0, 0);
}

// ---- fused fp32->bf16 convert (x + 4 weights) + RoPE tables, one launch ----
// ranges: [0, 2097152) x float4 | [2097152, 6291456) weights float4 |
//         [6291456, 6422528) rope tables (t = j>>6, i = j&63)
__global__ void k_cvt5(const float* __restrict__ x,  const float* __restrict__ wq,
                       const float* __restrict__ wk, const float* __restrict__ wv,
                       const float* __restrict__ wo,
                       unsigned short* __restrict__ xb,  unsigned short* __restrict__ wqb,
                       unsigned short* __restrict__ wkb, unsigned short* __restrict__ wvb,
                       unsigned short* __restrict__ wob,
                       float* __restrict__ ct, float* __restrict__ st) {
  int idx = blockIdx.x * blockDim.x + threadIdx.x;
  int stride = gridDim.x * blockDim.x;
  for (int i = idx; i < 6422528; i += stride) {
    if (i >= 6291456) { // rope tables
      int j = i - 6291456;
      int t = j >> 6, fi = j & 63;
      float invf = exp2f(-(float)fi * (13.287712379549449f / 64.0f));
      float a = (float)t * invf;
      ct[j] = cosf(a);
      st[j] = sinf(a);
      continue;
    }
    const float* src; unsigned short* dst; int off;
    if (i < 2097152) { src = x; dst = xb; off = i; }
    else {
      int j = i - 2097152;
      int w = j >> 20;            // 1,048,576 float4 per weight
      off = j & 1048575;
      src = (w == 0) ? wq : (w == 1) ? wk : (w == 2) ? wv : wo;
      dst = (w == 0) ? wqb : (w == 1) ? wkb : (w == 2) ? wvb : wob;
    }
    float4 f = ((const float4*)src)[off];
    ushort4 o;
    o.x = f2bf(f.x); o.y = f2bf(f.y); o.z = f2bf(f.z); o.w = f2bf(f.w);
    ((ushort4*)dst)[off] = o;
  }
}

// ---- RoPE apply in-place on q and k [BH, T, 128] bf16 ---------------------
// q pre-scaled by (1/sqrt(128))*log2(e): flash logits are base-2.
__global__ void k_rope(unsigned short* __restrict__ q, unsigned short* __restrict__ k,
                       const float* __restrict__ ct, const float* __restrict__ st) {
  const float SC2 = 0.12751659974141322f;
  int idx = blockIdx.x * blockDim.x + threadIdx.x;
  int i = idx & 63;
  int t = (idx >> 6) & 2047;
  int bh = idx >> 17;
  size_t base = ((size_t)bh * 2048 + t) * 128;
  float c = ct[t * 64 + i], s = st[t * 64 + i];
  {
    float x1 = bf2f(q[base + i]), x2 = bf2f(q[base + i + 64]);
    q[base + i]      = f2bf((x1 * c - x2 * s) * SC2);
    q[base + i + 64] = f2bf((x2 * c + x1 * s) * SC2);
  }
  {
    float x1 = bf2f(k[base + i]), x2 = bf2f(k[base + i + 64]);
    k[base + i]      = f2bf(x1 * c - x2 * s);
    k[base + i + 64] = f2bf(x2 * c + x1 * s);
  }
}

// ---- 256x256 8-phase GEMM (m201 template; EXACT r10 form) -----------------
template <int MODE>
__global__ __launch_bounds__(512, 2) void k_gemm256(
    const unsigned short* __restrict__ Ag,
    const unsigned short* __restrict__ B0,
    const unsigned short* __restrict__ B1,
    const unsigned short* __restrict__ B2,
    float* __restrict__ outF,
    unsigned short* __restrict__ outQ,
    unsigned short* __restrict__ outK,
    unsigned short* __restrict__ outVT) {
  __shared__ __align__(16) unsigned short lds[65536]; // 128 KiB

  const int tid = threadIdx.x;
  const int wid = tid >> 6, lane = tid & 63;
  const int wm = wid >> 2, wn = wid & 3;
  const int rowA = lane & 15, kg = lane >> 4;
  const int rgrp = kg * 4;
  const int swz = rowA & 7;

  const int m0 = blockIdx.y * 256;
  const int n0g = blockIdx.x * 256;
  int w, n0;
  const unsigned short* Bg;
  if (MODE == 0) { w = 0; n0 = n0g; Bg = B0; }
  else { w = n0g >> 11; n0 = n0g & 2047; Bg = (w == 0) ? B0 : (w == 1) ? B1 : B2; }

  const int aBase = wm * 8192 + rowA * 64;
  const int bBase = (wn >> 1) * 8192 + ((wn & 1) * 64 + rowA) * 64;
  const int ch0 = (kg ^ swz) * 8;
  const int ch1 = ((4 + kg) ^ swz) * 8;

  const int grow = wid * 8 + (lane >> 3);
  const int gch  = ((lane & 7) ^ ((lane >> 3) & 7)) * 8;
  const int sdst = wid * 512;

  auto SA = [&](int dst, int t1, int h, int j) {
    gload_lds16(Ag + (size_t)(m0 + h * 128 + j * 64 + grow) * 2048 + t1 * 64 + gch,
                (void*)&lds[dst * 16384 + h * 8192 + j * 4096 + sdst]);
  };
  auto SB = [&](int dst, int t1, int h, int j) {
    gload_lds16(Bg + (size_t)(n0 + h * 128 + j * 64 + grow) * 2048 + t1 * 64 + gch,
                (void*)&lds[32768 + dst * 16384 + h * 8192 + j * 4096 + sdst]);
  };

  f32x4 acc[8][4];
  const f32x4 z4 = {0.f, 0.f, 0.f, 0.f};
#pragma unroll
  for (int i = 0; i < 8; ++i)
#pragma unroll
    for (int j = 0; j < 4; ++j) acc[i][j] = z4;

  SA(0, 0, 0, 0); SA(0, 0, 0, 1); SA(0, 0, 1, 0); SA(0, 0, 1, 1);
  SB(0, 0, 0, 0); SB(0, 0, 0, 1); SB(0, 0, 1, 0); SB(0, 0, 1, 1);
  __syncthreads();

  for (int t = 0; t < 32; ++t) {
    const int c = t & 1, d = c ^ 1;
    const int cA = c * 16384, cB = 32768 + c * 16384;
    const bool pre = (t + 1 < 32);
    const int t1 = t + 1;
    bf16x8 af[4], af2[4], bk[4];

#pragma unroll
    for (int i = 0; i < 4; ++i) af[i] = *(const bf16x8*)&lds[cA + aBase + i * 1024 + ch0];
#pragma unroll
    for (int j = 0; j < 4; ++j) bk[j] = *(const bf16x8*)&lds[cB + bBase + j * 1024 + ch0];
    if (pre) { SA(d, t1, 0, 0); SA(d, t1, 0, 1); }
    __builtin_amdgcn_s_barrier();
    __builtin_amdgcn_sched_barrier(0);
    __builtin_amdgcn_s_setprio(1);
#pragma unroll
    for (int i = 0; i < 4; ++i)
#pragma unroll
      for (int j = 0; j < 4; ++j)
        acc[i][j] = __builtin_amdgcn_mfma_f32_16x16x32_bf16(af[i], bk[j], acc[i][j], 0, 0, 0);
    __builtin_amdgcn_s_setprio(0);
    __builtin_amdgcn_s_barrier();
    __builtin_amdgcn_sched_barrier(0);

#pragma unroll
    for (int i = 0; i < 4; ++i) af2[i] = *(const bf16x8*)&lds[cA + aBase + (i + 4) * 1024 + ch0];
    if (pre) { SA(d, t1, 1, 0); SA(d, t1, 1, 1); }
    __builtin_amdgcn_s_barrier();
    __builtin_amdgcn_sched_barrier(0);
    __builtin_amdgcn_s_setprio(1);
#pragma unroll
    for (int i = 0; i < 4; ++i)
#pragma unroll
      for (int j = 0; j < 4; ++j)
        acc[i + 4][j] = __builtin_amdgcn_mfma_f32_16x16x32_bf16(af2[i], bk[j], acc[i + 4][j], 0, 0, 0);
    __builtin_amdgcn_s_setprio(0);
    __builtin_amdgcn_s_barrier();
    __builtin_amdgcn_sched_barrier(0);

#pragma unroll
    for (int i = 0; i < 4; ++i) af[i] = *(const bf16x8*)&lds[cA + aBase + i * 1024 + ch1];
#pragma unroll
    for (int j = 0; j < 4; ++j) bk[j] = *(const bf16x8*)&lds[cB + bBase + j * 1024 + ch1];
    if (pre) { SB(d, t1, 0, 0); SB(d, t1, 0, 1); }
    __builtin_amdgcn_s_barrier();
    __builtin_amdgcn_sched_barrier(0);
    __builtin_amdgcn_s_setprio(1);
#pragma unroll
    for (int i = 0; i < 4; ++i)
#pragma unroll
      for (int j = 0; j < 4; ++j)
        acc[i][j] = __builtin_amdgcn_mfma_f32_16x16x32_bf16(af[i], bk[j], acc[i][j], 0, 0, 0);
    __builtin_amdgcn_s_setprio(0);
    __builtin_amdgcn_s_barrier();
    __builtin_amdgcn_sched_barrier(0);

#pragma unroll
    for (int i = 0; i < 4; ++i) af2[i] = *(const bf16x8*)&lds[cA + aBase + (i + 4) * 1024 + ch1];
    if (pre) { SB(d, t1, 1, 0); SB(d, t1, 1, 1); }
    __builtin_amdgcn_s_barrier();
    __builtin_amdgcn_sched_barrier(0);
    __builtin_amdgcn_s_setprio(1);
#pragma unroll
    for (int i = 0; i < 4; ++i)
#pragma unroll
      for (int j = 0; j < 4; ++j)
        acc[i + 4][j] = __builtin_amdgcn_mfma_f32_16x16x32_bf16(af2[i], bk[j], acc[i + 4][j], 0, 0, 0);
    __builtin_amdgcn_s_setprio(0);
    __syncthreads();
  }

#pragma unroll
  for (int i = 0; i < 8; ++i) {
#pragma unroll
    for (int j = 0; j < 4; ++j) {
      const int gm0 = m0 + wm * 128 + i * 16 + rgrp;
      const int gn  = n0 + wn * 64 + j * 16 + rowA;
      if (MODE == 0) {
#pragma unroll
        for (int r = 0; r < 4; ++r)
          outF[(size_t)(gm0 + r) * 2048 + gn] = acc[i][j][r];
      } else if (w == 2) {
        int h = gn >> 7, dd = gn & 127;
        int b = gm0 >> 11, tt = gm0 & 2047;
        ushort4 pk;
        pk.x = f2bf(acc[i][j][0]); pk.y = f2bf(acc[i][j][1]);
        pk.z = f2bf(acc[i][j][2]); pk.w = f2bf(acc[i][j][3]);
        *(ushort4*)&outVT[(((size_t)(b * 16 + h)) * 128 + dd) * 2048 + tt] = pk;
      } else {
        unsigned short* C = w ? outK : outQ;
        int h = gn >> 7, dd = gn & 127;
        int b = gm0 >> 11, tt = gm0 & 2047;
#pragma unroll
        for (int r = 0; r < 4; ++r)
          C[(((size_t)(b * 16 + h)) * 2048 + tt + r) * 128 + dd] = f2bf(acc[i][j][r]);
      }
    }
  }
}

// ---- output-projection GEMM: f32 out [M,N] (m97 structure) ----------------
__global__ __launch_bounds__(256) void k_gemm_o(const unsigned short* __restrict__ A,
                                                const unsigned short* __restrict__ Bw,
                                                float* __restrict__ Cout,
                                                int M, int N, int K) {
  __shared__ __align__(16) unsigned short As[128 * 64];
  __shared__ __align__(16) unsigned short Bs[128 * 64];

  const int tid = threadIdx.x;
  const int wid = tid >> 6, lane = tid & 63;
  const int wm = wid >> 1, wn = wid & 1;
  const int m0 = blockIdx.y * 128, n0 = blockIdx.x * 128;
  const int rowA = lane & 15;
  const int kgrp = (lane >> 4) * 8;
  const int rgrp = (lane >> 4) * 4;
  const int srow = lane >> 3;
  const int scol = (lane & 7) * 8;

  f32x4 acc[4][4];
  const f32x4 z4 = {0.f, 0.f, 0.f, 0.f};
#pragma unroll
  for (int i = 0; i < 4; ++i)
#pragma unroll
    for (int j = 0; j < 4; ++j) acc[i][j] = z4;

  for (int k0 = 0; k0 < K; k0 += 64) {
    __syncthreads();
#pragma unroll
    for (int i = 0; i < 4; ++i) {
      int c = wid * 4 + i;
      const unsigned short* ga = A  + (size_t)(m0 + c * 8 + srow) * K + k0 + scol;
      gload_lds16(ga, (void*)&As[c * 512]);
      const unsigned short* gb = Bw + (size_t)(n0 + c * 8 + srow) * K + k0 + scol;
      gload_lds16(gb, (void*)&Bs[c * 512]);
    }
    __syncthreads();
#pragma unroll
    for (int kk = 0; kk < 64; kk += 32) {
      bf16x8 af[4], bfv[4];
#pragma unroll
      for (int i = 0; i < 4; ++i)
        af[i] = *(const bf16x8*)&As[(wm * 64 + i * 16 + rowA) * 64 + kk + kgrp];
#pragma unroll
      for (int j = 0; j < 4; ++j)
        bfv[j] = *(const bf16x8*)&Bs[(wn * 64 + j * 16 + rowA) * 64 + kk + kgrp];
#pragma unroll
      for (int i = 0; i < 4; ++i)
#pragma unroll
        for (int j = 0; j < 4; ++j)
          acc[i][j] = __builtin_amdgcn_mfma_f32_16x16x32_bf16(af[i], bfv[j], acc[i][j], 0, 0, 0);
    }
  }

#pragma unroll
  for (int i = 0; i < 4; ++i)
#pragma unroll
    for (int j = 0; j < 4; ++j)
#pragma unroll
      for (int r = 0; r < 4; ++r) {
        int gm = m0 + wm * 64 + i * 16 + rgrp + r;
        int gn = n0 + wn * 64 + j * 16 + rowA;
        Cout[(size_t)gm * N + gn] = acc[i][j][r];
      }
}

// ---- flash attention fwd: EXACT r17 kernel (verified 128.5us) -------------
// 256-thr, KVBLK=128, 64KB LDS (P overlays K's dead space). Plateau: every
// 4-wave variant pins at ~11% occupancy regardless of LDS/VGPR/grid
// (r8,r11,r15-r18); this is the best-measured flash configuration.
__global__ __launch_bounds__(256) void k_flash(const unsigned short* __restrict__ q,
                                               const unsigned short* __restrict__ k,
                                               const unsigned short* __restrict__ vt,
                                               unsigned short* __restrict__ obt) {
  // ush: K[16384] @0 (P overlays [0,8192)) | V[16384] @16384   (= 64 KiB)
  __shared__ __align__(16) unsigned short lds[32768];

  const int tid = threadIdx.x;
  const int wid = tid >> 6, lane = tid & 63;
  const int rowA = lane & 15, kg = lane >> 4;
  const int kgrp = kg * 8, rgrp = kg * 4;

  const int bid = blockIdx.x;          // 0..255
  const int xcd = bid & 7;             // round-robin XCD dispatch (perf-only)
  const int r0  = bid >> 3;            // 0..31
  const int bh  = xcd * 4 + (r0 & 3);  // 4 heads per XCD chunk
  const int p   = r0 >> 2;             // 0..7
  const int b = bh >> 4, h = bh & 15;

  const int jbs[2] = {15 - p, p};      // heavy segment first
  const int nt0 = jbs[0] + 1, nt1 = jbs[1] + 1; // 128-wide tiles per segment
  const int total = nt0 + nt1;         // = 17 for every block

  const unsigned short* qh  = q  + (size_t)bh * 2048 * 128;
  const unsigned short* kh  = k  + (size_t)bh * 2048 * 128;
  const unsigned short* vth = vt + (size_t)bh * 128 * 2048;

  // staging: wave covers rows wid*32 + i*4 + (lane>>4), i=0..7; 16 lanes/row
  const int srow = wid * 32 + (lane >> 4);
  auto STAGE_K = [&](int kv0) {
#pragma unroll
    for (int i = 0; i < 8; ++i) {
      int row = srow + i * 4;
      int ch  = (lane & 15) ^ (row & 7);
      gload_lds16(kh + (size_t)(kv0 + row) * 128 + ch * 8,
                  (void*)&lds[wid * 4096 + i * 512]);
    }
  };
  auto STAGE_V = [&](int kv0) {
#pragma unroll
    for (int i = 0; i < 8; ++i) {
      int row = srow + i * 4;               // d-dim row
      int ch  = (lane & 15) ^ (row & 7);
      gload_lds16(vth + (size_t)row * 2048 + kv0 + ch * 8,
                  (void*)&lds[16384 + wid * 4096 + i * 512]);
    }
  };

  const f32x4 z4 = {0.f, 0.f, 0.f, 0.f};
  bf16x8 qf[2][4];
  f32x4 o[2][8];
  float mprev[2][4], lsum[2][4];
  int q0w = 0;

  int seg = 0, it = 0;
  STAGE_K(0);   // 8 oldest vmem ops
  STAGE_V(0);   // 8 newest

  for (int u = 0; u < total; ++u) {
    const int nt = (seg == 0) ? nt0 : nt1;
    const int kv0 = it * 128;

    // ---- top gate: K(u) complete everywhere; V(u) may still fly ----
    asm volatile("s_waitcnt vmcnt(8)" ::: "memory");
    __builtin_amdgcn_s_barrier();
    __builtin_amdgcn_sched_barrier(0);

    if (it == 0) {   // segment init: Q fragments + state reset
      q0w = jbs[seg] * 128 + wid * 32;
#pragma unroll
      for (int m = 0; m < 2; ++m)
#pragma unroll
        for (int kq = 0; kq < 4; ++kq)
          qf[m][kq] = *(const bf16x8*)(qh + (size_t)(q0w + m * 16 + rowA) * 128 + kq * 32 + kgrp);
#pragma unroll
      for (int m = 0; m < 2; ++m) {
#pragma unroll
        for (int dn = 0; dn < 8; ++dn) o[m][dn] = z4;
#pragma unroll
        for (int r2 = 0; r2 < 4; ++r2) { mprev[m][r2] = -1e30f; lsum[m][r2] = 0.f; }
      }
    }

    // ---- S = Q K^T over 128 kv (swizzled LDS) ----
    f32x4 s[2][8];
#pragma unroll
    for (int m = 0; m < 2; ++m)
#pragma unroll
      for (int n = 0; n < 8; ++n) s[m][n] = z4;
    __builtin_amdgcn_s_setprio(1);
#pragma unroll
    for (int kq = 0; kq < 4; ++kq) {
#pragma unroll
      for (int n = 0; n < 8; ++n) {
        int row = n * 16 + rowA;
        int ch  = (kq * 4 + kg) ^ (row & 7);
        bf16x8 bkk = *(const bf16x8*)&lds[row * 128 + ch * 8];
#pragma unroll
        for (int m = 0; m < 2; ++m)
          s[m][n] = __builtin_amdgcn_mfma_f32_16x16x32_bf16(qf[m][kq], bkk, s[m][n], 0, 0, 0);
      }
    }
    __builtin_amdgcn_s_setprio(0);

    // ---- mid gate: V(u) drained + K reads done -> P region free, V visible
    asm volatile("s_waitcnt vmcnt(0) lgkmcnt(0)" ::: "memory");
    __builtin_amdgcn_s_barrier();
    __builtin_amdgcn_sched_barrier(0);

    // ---- causal mask (only the diagonal tile) ----
    if (kv0 + 127 > q0w) {
#pragma unroll
      for (int m = 0; m < 2; ++m)
#pragma unroll
        for (int n = 0; n < 8; ++n)
#pragma unroll
          for (int r2 = 0; r2 < 4; ++r2) {
            int qg = q0w + m * 16 + rgrp + r2;
            int kgl = kv0 + n * 16 + rowA;
            if (kgl > qg) s[m][n][r2] = -1e30f;
          }
    }

    // ---- online softmax (base-2), step-major trees, defer-max ----
    float tmax[2][4];
#pragma unroll
    for (int m = 0; m < 2; ++m)
#pragma unroll
      for (int r2 = 0; r2 < 4; ++r2) {
        float t = s[m][0][r2];
#pragma unroll
        for (int n = 1; n < 8; ++n) t = fmaxf(t, s[m][n][r2]);
        tmax[m][r2] = t;
      }
#pragma unroll
    for (int stp = 1; stp <= 8; stp <<= 1)
#pragma unroll
      for (int m = 0; m < 2; ++m)
#pragma unroll
        for (int r2 = 0; r2 < 4; ++r2)
          tmax[m][r2] = fmaxf(tmax[m][r2], __shfl_xor(tmax[m][r2], stp));

    bool ok = true;
#pragma unroll
    for (int m = 0; m < 2; ++m)
#pragma unroll
      for (int r2 = 0; r2 < 4; ++r2) ok = ok && (tmax[m][r2] <= mprev[m][r2] + 8.0f);
    const bool skip = __all(ok ? 1 : 0);

    float mnew[2][4], psum[2][4];
#pragma unroll
    for (int m = 0; m < 2; ++m)
#pragma unroll
      for (int r2 = 0; r2 < 4; ++r2) {
        mnew[m][r2] = skip ? mprev[m][r2] : fmaxf(mprev[m][r2], tmax[m][r2]);
        float ps = 0.f;
#pragma unroll
        for (int n = 0; n < 8; ++n) {
          float pp = exp2f(s[m][n][r2] - mnew[m][r2]);
          s[m][n][r2] = pp;
          ps += pp;
        }
        psum[m][r2] = ps;
      }
#pragma unroll
    for (int stp = 1; stp <= 8; stp <<= 1)
#pragma unroll
      for (int m = 0; m < 2; ++m)
#pragma unroll
        for (int r2 = 0; r2 < 4; ++r2)
          psum[m][r2] += __shfl_xor(psum[m][r2], stp);

#pragma unroll
    for (int m = 0; m < 2; ++m)
#pragma unroll
      for (int r2 = 0; r2 < 4; ++r2) {
        if (skip) {
          lsum[m][r2] += psum[m][r2];
        } else {
          float alpha = exp2f(mprev[m][r2] - mnew[m][r2]);
          lsum[m][r2] = lsum[m][r2] * alpha + psum[m][r2];
          mprev[m][r2] = mnew[m][r2];
#pragma unroll
          for (int dn = 0; dn < 8; ++dn) o[m][dn][r2] *= alpha;
        }
      }

    // ---- PV in two passes; P overlays Kbuf[0..8192) (K dead, barrier'd) ----
    unsigned short* Pw = &lds[wid * 2048];
    const unsigned short* Vb = &lds[16384];
#pragma unroll
    for (int pass = 0; pass < 2; ++pass) {
#pragma unroll
      for (int m = 0; m < 2; ++m)
#pragma unroll
        for (int nl = 0; nl < 4; ++nl)
#pragma unroll
          for (int r2 = 0; r2 < 4; ++r2) {
            int row = m * 16 + rgrp + r2;
            int col = nl * 16 + rowA;
            Pw[row * 64 + (col ^ ((row & 7) << 3))] = f2bf(s[m][pass * 4 + nl][r2]);
          }
      // per-wave DS ordering: compiler inserts lgkmcnt waits before reads
      __builtin_amdgcn_s_setprio(1);
#pragma unroll
      for (int kkl = 0; kkl < 2; ++kkl) {
        const int kk = pass * 2 + kkl;
        bf16x8 pa[2];
#pragma unroll
        for (int m = 0; m < 2; ++m) {
          int row = m * 16 + rowA;
          int col0 = kkl * 32 + kgrp;
          pa[m] = *(const bf16x8*)&Pw[row * 64 + (col0 ^ ((row & 7) << 3))];
        }
#pragma unroll
        for (int dn = 0; dn < 8; ++dn) {
          int row = dn * 16 + rowA;
          int ch  = (kk * 4 + kg) ^ (row & 7);
          bf16x8 vb = *(const bf16x8*)&Vb[row * 128 + ch * 8];
#pragma unroll
          for (int m = 0; m < 2; ++m)
            o[m][dn] = __builtin_amdgcn_mfma_f32_16x16x32_bf16(pa[m], vb, o[m][dn], 0, 0, 0);
        }
      }
      __builtin_amdgcn_s_setprio(0);
    }

    // ---- segment epilogue: normalize and write ----
    if (it == nt - 1) {
      float rinv[2][4];
#pragma unroll
      for (int m = 0; m < 2; ++m)
#pragma unroll
        for (int r2 = 0; r2 < 4; ++r2) rinv[m][r2] = 1.0f / lsum[m][r2];
#pragma unroll
      for (int m = 0; m < 2; ++m)
#pragma unroll
        for (int dn = 0; dn < 8; ++dn)
#pragma unroll
          for (int r2 = 0; r2 < 4; ++r2) {
            float v = o[m][dn][r2] * rinv[m][r2];
            int t = q0w + m * 16 + rgrp + r2;
            int col = h * 128 + dn * 16 + rowA;
            obt[((size_t)b * 2048 + t) * 2048 + col] = f2bf(v);
          }
    }

    __syncthreads(); // all P/V reads done; buffers reusable

    // ---- stage next K and V (K first = oldest; drained at next top gate) --
    if (u + 1 < total) {
      const int itn = (u + 1 >= nt0) ? (u + 1 - nt0) : (u + 1);
      STAGE_K(itn * 128);
      STAGE_V(itn * 128);
    }

    ++it;
    if (seg == 0 && it == nt0) { seg = 1; it = 0; }
  }
}

// ---- host launch -----------------------------------------------------------
extern "C" void kernel_launch(void* const* d_in, const int* in_sizes, int n_in,
                              void* d_out, int out_size, void* d_ws, size_t ws_size,
                              hipStream_t stream) {
  const float* x  = (const float*)d_in[0];
  const float* Wq = (const float*)d_in[2];
  const float* Wk = (const float*)d_in[3];
  const float* Wv = (const float*)d_in[4];
  const float* Wo = (const float*)d_in[5];
  float* out = (float*)d_out;

  char* ws = (char*)d_ws;
  unsigned short* xb  = (unsigned short*)(ws + 0);
  unsigned short* wqb = (unsigned short*)(ws + 16777216);
  unsigned short* wkb = (unsigned short*)(ws + 25165824);
  unsigned short* wvb = (unsigned short*)(ws + 33554432);
  unsigned short* wob = (unsigned short*)(ws + 41943040);
  unsigned short* qb  = (unsigned short*)(ws + 50331648);
  unsigned short* kb  = (unsigned short*)(ws + 67108864);
  unsigned short* vtb = (unsigned short*)(ws + 83886080);
  unsigned short* obt = (unsigned short*)(ws + 100663296);
  float* ct = (float*)(ws + 117440512);
  float* st = (float*)(ws + 117964800);

  k_cvt5<<<2048, 256, 0, stream>>>(x, Wq, Wk, Wv, Wo, xb, wqb, wkb, wvb, wob, ct, st);
  dim3 gq(24, 16); // merged QKV: 6144/256 x 4096/256, 512 thr
  k_gemm256<1><<<gq, 512, 0, stream>>>(xb, wqb, wkb, wvb, nullptr, qb, kb, vtb);
  k_rope<<<16384, 256, 0, stream>>>(qb, kb, ct, st);
  k_flash<<<256, 256, 0, stream>>>(qb, kb, vtb, obt);
  dim3 gg(16, 32);
  k_gemm_o<<<gg, 256, 0, stream>>>(obt, wob, out, 4096, 2048, 2048);
}

// Round 20
// 302.389 us; speedup vs baseline: 1.1535x; 1.0333x over previous
//
#include <hip/hip_runtime.h>
#include <stdint.h>

#define AS1 __attribute__((address_space(1)))
#define AS3 __attribute__((address_space(3)))

using bf16x8 = __attribute__((ext_vector_type(8))) short;
using f32x4  = __attribute__((ext_vector_type(4))) float;

// ---- helpers -------------------------------------------------------------
__device__ __forceinline__ unsigned short f2bf(float f) {
  union { float f; unsigned u; } v; v.f = f;
  return (unsigned short)((v.u + 0x7FFFu + ((v.u >> 16) & 1u)) >> 16); // RNE
}
__device__ __forceinline__ float bf2f(unsigned short h) {
  union { unsigned u; float f; } v; v.u = ((unsigned)h) << 16;
  return v.f;
}
// async global->LDS, 16B per lane; lds dest must be wave-uniform base (HW adds lane*16)
__device__ __forceinline__ void gload_lds16(const void* g, void* l) {
  __builtin_amdgcn_global_load_lds((AS1 const void*)g, (AS3 void*)l, 16, 0, 0);
}

// ---- fused fp32->bf16 convert (x + 4 weights) + RoPE tables, one launch ----
__global__ void k_cvt5(const float* __restrict__ x,  const float* __restrict__ wq,
                       const float* __restrict__ wk, const float* __restrict__ wv,
                       const float* __restrict__ wo,
                       unsigned short* __restrict__ xb,  unsigned short* __restrict__ wqb,
                       unsigned short* __restrict__ wkb, unsigned short* __restrict__ wvb,
                       unsigned short* __restrict__ wob,
                       float* __restrict__ ct, float* __restrict__ st) {
  int idx = blockIdx.x * blockDim.x + threadIdx.x;
  int stride = gridDim.x * blockDim.x;
  for (int i = idx; i < 6422528; i += stride) {
    if (i >= 6291456) { // rope tables
      int j = i - 6291456;
      int t = j >> 6, fi = j & 63;
      float invf = exp2f(-(float)fi * (13.287712379549449f / 64.0f));
      float a = (float)t * invf;
      ct[j] = cosf(a);
      st[j] = sinf(a);
      continue;
    }
    const float* src; unsigned short* dst; int off;
    if (i < 2097152) { src = x; dst = xb; off = i; }
    else {
      int j = i - 2097152;
      int w = j >> 20;            // 1,048,576 float4 per weight
      off = j & 1048575;
      src = (w == 0) ? wq : (w == 1) ? wk : (w == 2) ? wv : wo;
      dst = (w == 0) ? wqb : (w == 1) ? wkb : (w == 2) ? wvb : wob;
    }
    float4 f = ((const float4*)src)[off];
    ushort4 o;
    o.x = f2bf(f.x); o.y = f2bf(f.y); o.z = f2bf(f.z); o.w = f2bf(f.w);
    ((ushort4*)dst)[off] = o;
  }
}

// ---- RoPE apply in-place on q and k [BH, T, 128] bf16 ---------------------
// q pre-scaled by (1/sqrt(128))*log2(e): flash logits are base-2.
__global__ void k_rope(unsigned short* __restrict__ q, unsigned short* __restrict__ k,
                       const float* __restrict__ ct, const float* __restrict__ st) {
  const float SC2 = 0.12751659974141322f;
  int idx = blockIdx.x * blockDim.x + threadIdx.x;
  int i = idx & 63;
  int t = (idx >> 6) & 2047;
  int bh = idx >> 17;
  size_t base = ((size_t)bh * 2048 + t) * 128;
  float c = ct[t * 64 + i], s = st[t * 64 + i];
  {
    float x1 = bf2f(q[base + i]), x2 = bf2f(q[base + i + 64]);
    q[base + i]      = f2bf((x1 * c - x2 * s) * SC2);
    q[base + i + 64] = f2bf((x2 * c + x1 * s) * SC2);
  }
  {
    float x1 = bf2f(k[base + i]), x2 = bf2f(k[base + i + 64]);
    k[base + i]      = f2bf(x1 * c - x2 * s);
    k[base + i + 64] = f2bf(x2 * c + x1 * s);
  }
}

// ---- 256x128 8-phase GEMM (BN=128 variant of the verified m201 template) ---
// Fixes grid/CU quantization: QKV grid = 48x16 = 768 blocks = 3 EVEN rounds
// (the 256x256 grid was 384 = 2 rounds, second half-idle); Wo grid = 16x16 =
// 256 blocks = 1 full-chip round. Same staging formulas / XOR involution /
// barrier skeleton as the verified kernel; wave grid 4M x 2N, acc[4][4],
// LDS 96KB (A dbuf 64KB + B dbuf 32KB), 2 compute phases x 16 MFMA with
// 3 staging calls each (4 SA + 2 SB per K-tile).
// MODE 0: f32 out [M,2048] (Wo).  MODE 1: merged QKV (w = n0g>>11).
template <int MODE>
__global__ __launch_bounds__(512, 2) void k_gemm256n128(
    const unsigned short* __restrict__ Ag,
    const unsigned short* __restrict__ B0,
    const unsigned short* __restrict__ B1,
    const unsigned short* __restrict__ B2,
    float* __restrict__ outF,
    unsigned short* __restrict__ outQ,
    unsigned short* __restrict__ outK,
    unsigned short* __restrict__ outVT) {
  // ush: A dbuf [2][16384] @0 | B dbuf [2][8192] @32768   (= 96 KiB)
  __shared__ __align__(16) unsigned short lds[49152];

  const int tid = threadIdx.x;
  const int wid = tid >> 6, lane = tid & 63;
  const int wm = wid >> 1, wn = wid & 1;      // 4M x 2N wave grid
  const int rowA = lane & 15, kg = lane >> 4;
  const int rgrp = kg * 4;
  const int swz = rowA & 7;

  const int m0 = blockIdx.y * 256;
  const int n0g = blockIdx.x * 128;
  int w, n0;
  const unsigned short* Bg;
  if (MODE == 0) { w = 0; n0 = n0g; Bg = B0; }
  else { w = n0g >> 11; n0 = n0g & 2047; Bg = (w == 0) ? B0 : (w == 1) ? B1 : B2; }

  const int aBase = wm * 4096 + rowA * 64;    // + i*1024 + ch, i<4
  const int bBase = wn * 4096 + rowA * 64;    // + j*1024 + ch, j<4
  const int ch0 = (kg ^ swz) * 8;             // kk=0 chunks 0..3
  const int ch1 = ((4 + kg) ^ swz) * 8;       // kk=1 chunks 4..7

  // staging: one call covers 64 rows (512 thr x 16B = 8KB)
  const int grow = wid * 8 + (lane >> 3);
  const int gch  = ((lane & 7) ^ ((lane >> 3) & 7)) * 8; // inverse-swizzled src
  const int sdst = wid * 512;

  auto SA = [&](int dst, int t1, int c4) {    // A: 256 rows = 4 chunks of 64
    gload_lds16(Ag + (size_t)(m0 + c4 * 64 + grow) * 2048 + t1 * 64 + gch,
                (void*)&lds[dst * 16384 + c4 * 4096 + sdst]);
  };
  auto SB = [&](int dst, int t1, int c2) {    // B: 128 rows = 2 chunks of 64
    gload_lds16(Bg + (size_t)(n0 + c2 * 64 + grow) * 2048 + t1 * 64 + gch,
                (void*)&lds[32768 + dst * 8192 + c2 * 4096 + sdst]);
  };

  f32x4 acc[4][4];
  const f32x4 z4 = {0.f, 0.f, 0.f, 0.f};
#pragma unroll
  for (int i = 0; i < 4; ++i)
#pragma unroll
    for (int j = 0; j < 4; ++j) acc[i][j] = z4;

  // prologue: stage K-tile 0 into buf 0, drain, publish
  SA(0, 0, 0); SA(0, 0, 1); SA(0, 0, 2); SA(0, 0, 3);
  SB(0, 0, 0); SB(0, 0, 1);
  __syncthreads();

  for (int t = 0; t < 32; ++t) {
    const int c = t & 1, d = c ^ 1;
    const int cA = c * 16384, cB = 32768 + c * 8192;
    const bool pre = (t + 1 < 32);
    const int t1 = t + 1;
    bf16x8 af[4], bk[4];

    // ---- phase 0: frags kk=0 | stage A[0..1],B[0] of t+1 | 16 MFMA
#pragma unroll
    for (int i = 0; i < 4; ++i) af[i] = *(const bf16x8*)&lds[cA + aBase + i * 1024 + ch0];
#pragma unroll
    for (int j = 0; j < 4; ++j) bk[j] = *(const bf16x8*)&lds[cB + bBase + j * 1024 + ch0];
    if (pre) { SA(d, t1, 0); SA(d, t1, 1); SB(d, t1, 0); }
    __builtin_amdgcn_s_barrier();
    __builtin_amdgcn_sched_barrier(0);
    __builtin_amdgcn_s_setprio(1);
#pragma unroll
    for (int i = 0; i < 4; ++i)
#pragma unroll
      for (int j = 0; j < 4; ++j)
        acc[i][j] = __builtin_amdgcn_mfma_f32_16x16x32_bf16(af[i], bk[j], acc[i][j], 0, 0, 0);
    __builtin_amdgcn_s_setprio(0);
    __builtin_amdgcn_s_barrier();
    __builtin_amdgcn_sched_barrier(0);

    // ---- phase 1: frags kk=1 | stage A[2..3],B[1] of t+1 | 16 MFMA | drain
#pragma unroll
    for (int i = 0; i < 4; ++i) af[i] = *(const bf16x8*)&lds[cA + aBase + i * 1024 + ch1];
#pragma unroll
    for (int j = 0; j < 4; ++j) bk[j] = *(const bf16x8*)&lds[cB + bBase + j * 1024 + ch1];
    if (pre) { SA(d, t1, 2); SA(d, t1, 3); SB(d, t1, 1); }
    __builtin_amdgcn_s_barrier();
    __builtin_amdgcn_sched_barrier(0);
    __builtin_amdgcn_s_setprio(1);
#pragma unroll
    for (int i = 0; i < 4; ++i)
#pragma unroll
      for (int j = 0; j < 4; ++j)
        acc[i][j] = __builtin_amdgcn_mfma_f32_16x16x32_bf16(af[i], bk[j], acc[i][j], 0, 0, 0);
    __builtin_amdgcn_s_setprio(0);
    __syncthreads(); // vmcnt(0)+lgkmcnt(0)+barrier: tile t+1 staged & visible
  }

  // ---- epilogue ----
#pragma unroll
  for (int i = 0; i < 4; ++i) {
#pragma unroll
    for (int j = 0; j < 4; ++j) {
      const int gm0 = m0 + wm * 64 + i * 16 + rgrp;
      const int gn  = n0 + wn * 64 + j * 16 + rowA;
      if (MODE == 0) {
#pragma unroll
        for (int r = 0; r < 4; ++r)
          outF[(size_t)(gm0 + r) * 2048 + gn] = acc[i][j][r];
      } else if (w == 2) { // transposed V
        int h = gn >> 7, dd = gn & 127;
        int b = gm0 >> 11, tt = gm0 & 2047;
        ushort4 pk;
        pk.x = f2bf(acc[i][j][0]); pk.y = f2bf(acc[i][j][1]);
        pk.z = f2bf(acc[i][j][2]); pk.w = f2bf(acc[i][j][3]);
        *(ushort4*)&outVT[(((size_t)(b * 16 + h)) * 128 + dd) * 2048 + tt] = pk;
      } else {
        unsigned short* C = w ? outK : outQ;
        int h = gn >> 7, dd = gn & 127;
        int b = gm0 >> 11, tt = gm0 & 2047;
#pragma unroll
        for (int r = 0; r < 4; ++r)
          C[(((size_t)(b * 16 + h)) * 2048 + tt + r) * 128 + dd] = f2bf(acc[i][j][r]);
      }
    }
  }
}

// ---- flash attention fwd: EXACT r17 kernel (verified 127.5us) -------------
__global__ __launch_bounds__(256) void k_flash(const unsigned short* __restrict__ q,
                                               const unsigned short* __restrict__ k,
                                               const unsigned short* __restrict__ vt,
                                               unsigned short* __restrict__ obt) {
  // ush: K[16384] @0 (P overlays [0,8192)) | V[16384] @16384   (= 64 KiB)
  __shared__ __align__(16) unsigned short lds[32768];

  const int tid = threadIdx.x;
  const int wid = tid >> 6, lane = tid & 63;
  const int rowA = lane & 15, kg = lane >> 4;
  const int kgrp = kg * 8, rgrp = kg * 4;

  const int bid = blockIdx.x;          // 0..255
  const int xcd = bid & 7;             // round-robin XCD dispatch (perf-only)
  const int r0  = bid >> 3;            // 0..31
  const int bh  = xcd * 4 + (r0 & 3);  // 4 heads per XCD chunk
  const int p   = r0 >> 2;             // 0..7
  const int b = bh >> 4, h = bh & 15;

  const int jbs[2] = {15 - p, p};      // heavy segment first
  const int nt0 = jbs[0] + 1, nt1 = jbs[1] + 1; // 128-wide tiles per segment
  const int total = nt0 + nt1;         // = 17 for every block

  const unsigned short* qh  = q  + (size_t)bh * 2048 * 128;
  const unsigned short* kh  = k  + (size_t)bh * 2048 * 128;
  const unsigned short* vth = vt + (size_t)bh * 128 * 2048;

  const int srow = wid * 32 + (lane >> 4);
  auto STAGE_K = [&](int kv0) {
#pragma unroll
    for (int i = 0; i < 8; ++i) {
      int row = srow + i * 4;
      int ch  = (lane & 15) ^ (row & 7);
      gload_lds16(kh + (size_t)(kv0 + row) * 128 + ch * 8,
                  (void*)&lds[wid * 4096 + i * 512]);
    }
  };
  auto STAGE_V = [&](int kv0) {
#pragma unroll
    for (int i = 0; i < 8; ++i) {
      int row = srow + i * 4;               // d-dim row
      int ch  = (lane & 15) ^ (row & 7);
      gload_lds16(vth + (size_t)row * 2048 + kv0 + ch * 8,
                  (void*)&lds[16384 + wid * 4096 + i * 512]);
    }
  };

  const f32x4 z4 = {0.f, 0.f, 0.f, 0.f};
  bf16x8 qf[2][4];
  f32x4 o[2][8];
  float mprev[2][4], lsum[2][4];
  int q0w = 0;

  int seg = 0, it = 0;
  STAGE_K(0);   // 8 oldest vmem ops
  STAGE_V(0);   // 8 newest

  for (int u = 0; u < total; ++u) {
    const int nt = (seg == 0) ? nt0 : nt1;
    const int kv0 = it * 128;

    // ---- top gate: K(u) complete everywhere; V(u) may still fly ----
    asm volatile("s_waitcnt vmcnt(8)" ::: "memory");
    __builtin_amdgcn_s_barrier();
    __builtin_amdgcn_sched_barrier(0);

    if (it == 0) {   // segment init: Q fragments + state reset
      q0w = jbs[seg] * 128 + wid * 32;
#pragma unroll
      for (int m = 0; m < 2; ++m)
#pragma unroll
        for (int kq = 0; kq < 4; ++kq)
          qf[m][kq] = *(const bf16x8*)(qh + (size_t)(q0w + m * 16 + rowA) * 128 + kq * 32 + kgrp);
#pragma unroll
      for (int m = 0; m < 2; ++m) {
#pragma unroll
        for (int dn = 0; dn < 8; ++dn) o[m][dn] = z4;
#pragma unroll
        for (int r2 = 0; r2 < 4; ++r2) { mprev[m][r2] = -1e30f; lsum[m][r2] = 0.f; }
      }
    }

    // ---- S = Q K^T over 128 kv (swizzled LDS) ----
    f32x4 s[2][8];
#pragma unroll
    for (int m = 0; m < 2; ++m)
#pragma unroll
      for (int n = 0; n < 8; ++n) s[m][n] = z4;
    __builtin_amdgcn_s_setprio(1);
#pragma unroll
    for (int kq = 0; kq < 4; ++kq) {
#pragma unroll
      for (int n = 0; n < 8; ++n) {
        int row = n * 16 + rowA;
        int ch  = (kq * 4 + kg) ^ (row & 7);
        bf16x8 bkk = *(const bf16x8*)&lds[row * 128 + ch * 8];
#pragma unroll
        for (int m = 0; m < 2; ++m)
          s[m][n] = __builtin_amdgcn_mfma_f32_16x16x32_bf16(qf[m][kq], bkk, s[m][n], 0, 0, 0);
      }
    }
    __builtin_amdgcn_s_setprio(0);

    // ---- mid gate: V(u) drained + K reads done -> P region free, V visible
    asm volatile("s_waitcnt vmcnt(0) lgkmcnt(0)" ::: "memory");
    __builtin_amdgcn_s_barrier();
    __builtin_amdgcn_sched_barrier(0);

    // ---- causal mask (only the diagonal tile) ----
    if (kv0 + 127 > q0w) {
#pragma unroll
      for (int m = 0; m < 2; ++m)
#pragma unroll
        for (int n = 0; n < 8; ++n)
#pragma unroll
          for (int r2 = 0; r2 < 4; ++r2) {
            int qg = q0w + m * 16 + rgrp + r2;
            int kgl = kv0 + n * 16 + rowA;
            if (kgl > qg) s[m][n][r2] = -1e30f;
          }
    }

    // ---- online softmax (base-2), step-major trees, defer-max ----
    float tmax[2][4];
#pragma unroll
    for (int m = 0; m < 2; ++m)
#pragma unroll
      for (int r2 = 0; r2 < 4; ++r2) {
        float t = s[m][0][r2];
#pragma unroll
        for (int n = 1; n < 8; ++n) t = fmaxf(t, s[m][n][r2]);
        tmax[m][r2] = t;
      }
#pragma unroll
    for (int stp = 1; stp <= 8; stp <<= 1)
#pragma unroll
      for (int m = 0; m < 2; ++m)
#pragma unroll
        for (int r2 = 0; r2 < 4; ++r2)
          tmax[m][r2] = fmaxf(tmax[m][r2], __shfl_xor(tmax[m][r2], stp));

    bool ok = true;
#pragma unroll
    for (int m = 0; m < 2; ++m)
#pragma unroll
      for (int r2 = 0; r2 < 4; ++r2) ok = ok && (tmax[m][r2] <= mprev[m][r2] + 8.0f);
    const bool skip = __all(ok ? 1 : 0);

    float mnew[2][4], psum[2][4];
#pragma unroll
    for (int m = 0; m < 2; ++m)
#pragma unroll
      for (int r2 = 0; r2 < 4; ++r2) {
        mnew[m][r2] = skip ? mprev[m][r2] : fmaxf(mprev[m][r2], tmax[m][r2]);
        float ps = 0.f;
#pragma unroll
        for (int n = 0; n < 8; ++n) {
          float pp = exp2f(s[m][n][r2] - mnew[m][r2]);
          s[m][n][r2] = pp;
          ps += pp;
        }
        psum[m][r2] = ps;
      }
#pragma unroll
    for (int stp = 1; stp <= 8; stp <<= 1)
#pragma unroll
      for (int m = 0; m < 2; ++m)
#pragma unroll
        for (int r2 = 0; r2 < 4; ++r2)
          psum[m][r2] += __shfl_xor(psum[m][r2], stp);

#pragma unroll
    for (int m = 0; m < 2; ++m)
#pragma unroll
      for (int r2 = 0; r2 < 4; ++r2) {
        if (skip) {
          lsum[m][r2] += psum[m][r2];
        } else {
          float alpha = exp2f(mprev[m][r2] - mnew[m][r2]);
          lsum[m][r2] = lsum[m][r2] * alpha + psum[m][r2];
          mprev[m][r2] = mnew[m][r2];
#pragma unroll
          for (int dn = 0; dn < 8; ++dn) o[m][dn][r2] *= alpha;
        }
      }

    // ---- PV in two passes; P overlays Kbuf[0..8192) (K dead, barrier'd) ----
    unsigned short* Pw = &lds[wid * 2048];
    const unsigned short* Vb = &lds[16384];
#pragma unroll
    for (int pass = 0; pass < 2; ++pass) {
#pragma unroll
      for (int m = 0; m < 2; ++m)
#pragma unroll
        for (int nl = 0; nl < 4; ++nl)
#pragma unroll
          for (int r2 = 0; r2 < 4; ++r2) {
            int row = m * 16 + rgrp + r2;
            int col = nl * 16 + rowA;
            Pw[row * 64 + (col ^ ((row & 7) << 3))] = f2bf(s[m][pass * 4 + nl][r2]);
          }
      // per-wave DS ordering: compiler inserts lgkmcnt waits before reads
      __builtin_amdgcn_s_setprio(1);
#pragma unroll
      for (int kkl = 0; kkl < 2; ++kkl) {
        const int kk = pass * 2 + kkl;
        bf16x8 pa[2];
#pragma unroll
        for (int m = 0; m < 2; ++m) {
          int row = m * 16 + rowA;
          int col0 = kkl * 32 + kgrp;
          pa[m] = *(const bf16x8*)&Pw[row * 64 + (col0 ^ ((row & 7) << 3))];
        }
#pragma unroll
        for (int dn = 0; dn < 8; ++dn) {
          int row = dn * 16 + rowA;
          int ch  = (kk * 4 + kg) ^ (row & 7);
          bf16x8 vb = *(const bf16x8*)&Vb[row * 128 + ch * 8];
#pragma unroll
          for (int m = 0; m < 2; ++m)
            o[m][dn] = __builtin_amdgcn_mfma_f32_16x16x32_bf16(pa[m], vb, o[m][dn], 0, 0, 0);
        }
      }
      __builtin_amdgcn_s_setprio(0);
    }

    // ---- segment epilogue: normalize and write ----
    if (it == nt - 1) {
      float rinv[2][4];
#pragma unroll
      for (int m = 0; m < 2; ++m)
#pragma unroll
        for (int r2 = 0; r2 < 4; ++r2) rinv[m][r2] = 1.0f / lsum[m][r2];
#pragma unroll
      for (int m = 0; m < 2; ++m)
#pragma unroll
        for (int dn = 0; dn < 8; ++dn)
#pragma unroll
          for (int r2 = 0; r2 < 4; ++r2) {
            float v = o[m][dn][r2] * rinv[m][r2];
            int t = q0w + m * 16 + rgrp + r2;
            int col = h * 128 + dn * 16 + rowA;
            obt[((size_t)b * 2048 + t) * 2048 + col] = f2bf(v);
          }
    }

    __syncthreads(); // all P/V reads done; buffers reusable

    // ---- stage next K and V (K first = oldest; drained at next top gate) --
    if (u + 1 < total) {
      const int itn = (u + 1 >= nt0) ? (u + 1 - nt0) : (u + 1);
      STAGE_K(itn * 128);
      STAGE_V(itn * 128);
    }

    ++it;
    if (seg == 0 && it == nt0) { seg = 1; it = 0; }
  }
}

// ---- host launch -----------------------------------------------------------
extern "C" void kernel_launch(void* const* d_in, const int* in_sizes, int n_in,
                              void* d_out, int out_size, void* d_ws, size_t ws_size,
                              hipStream_t stream) {
  const float* x  = (const float*)d_in[0];
  const float* Wq = (const float*)d_in[2];
  const float* Wk = (const float*)d_in[3];
  const float* Wv = (const float*)d_in[4];
  const float* Wo = (const float*)d_in[5];
  float* out = (float*)d_out;

  char* ws = (char*)d_ws;
  unsigned short* xb  = (unsigned short*)(ws + 0);
  unsigned short* wqb = (unsigned short*)(ws + 16777216);
  unsigned short* wkb = (unsigned short*)(ws + 25165824);
  unsigned short* wvb = (unsigned short*)(ws + 33554432);
  unsigned short* wob = (unsigned short*)(ws + 41943040);
  unsigned short* qb  = (unsigned short*)(ws + 50331648);
  unsigned short* kb  = (unsigned short*)(ws + 67108864);
  unsigned short* vtb = (unsigned short*)(ws + 83886080);
  unsigned short* obt = (unsigned short*)(ws + 100663296);
  float* ct = (float*)(ws + 117440512);
  float* st = (float*)(ws + 117964800);

  k_cvt5<<<2048, 256, 0, stream>>>(x, Wq, Wk, Wv, Wo, xb, wqb, wkb, wvb, wob, ct, st);
  dim3 gq(48, 16); // merged QKV: 6144/128 x 4096/256 = 768 blocks = 3 even rounds
  k_gemm256n128<1><<<gq, 512, 0, stream>>>(xb, wqb, wkb, wvb, nullptr, qb, kb, vtb);
  k_rope<<<16384, 256, 0, stream>>>(qb, kb, ct, st);
  k_flash<<<256, 256, 0, stream>>>(qb, kb, vtb, obt);
  dim3 go(16, 16); // Wo: 2048/128 x 4096/256 = 256 blocks = 1 full-chip round
  k_gemm256n128<0><<<go, 512, 0, stream>>>(obt, wob, nullptr, nullptr, out, nullptr, nullptr, nullptr);
}

// Round 21
// 274.674 us; speedup vs baseline: 1.2698x; 1.1009x over previous
//
#include <hip/hip_runtime.h>
#include <stdint.h>

#define AS1 __attribute__((address_space(1)))
#define AS3 __attribute__((address_space(3)))

using bf16x8 = __attribute__((ext_vector_type(8))) short;
using f32x4  = __attribute__((ext_vector_type(4))) float;

// ---- helpers -------------------------------------------------------------
__device__ __forceinline__ unsigned short f2bf(float f) {
  union { float f; unsigned u; } v; v.f = f;
  return (unsigned short)((v.u + 0x7FFFu + ((v.u >> 16) & 1u)) >> 16); // RNE
}
__device__ __forceinline__ float bf2f(unsigned short h) {
  union { unsigned u; float f; } v; v.u = ((unsigned)h) << 16;
  return v.f;
}
// async global->LDS, 16B per lane; lds dest must be wave-uniform base (HW adds lane*16)
__device__ __forceinline__ void gload_lds16(const void* g, void* l) {
  __builtin_amdgcn_global_load_lds((AS1 const void*)g, (AS3 void*)l, 16, 0, 0);
}

// ---- fused fp32->bf16 convert (x + 4 weights) + RoPE tables, one launch ----
__global__ void k_cvt5(const float* __restrict__ x,  const float* __restrict__ wq,
                       const float* __restrict__ wk, const float* __restrict__ wv,
                       const float* __restrict__ wo,
                       unsigned short* __restrict__ xb,  unsigned short* __restrict__ wqb,
                       unsigned short* __restrict__ wkb, unsigned short* __restrict__ wvb,
                       unsigned short* __restrict__ wob,
                       float* __restrict__ ct, float* __restrict__ st) {
  int idx = blockIdx.x * blockDim.x + threadIdx.x;
  int stride = gridDim.x * blockDim.x;
  for (int i = idx; i < 6422528; i += stride) {
    if (i >= 6291456) { // rope tables
      int j = i - 6291456;
      int t = j >> 6, fi = j & 63;
      float invf = exp2f(-(float)fi * (13.287712379549449f / 64.0f));
      float a = (float)t * invf;
      ct[j] = cosf(a);
      st[j] = sinf(a);
      continue;
    }
    const float* src; unsigned short* dst; int off;
    if (i < 2097152) { src = x; dst = xb; off = i; }
    else {
      int j = i - 2097152;
      int w = j >> 20;            // 1,048,576 float4 per weight
      off = j & 1048575;
      src = (w == 0) ? wq : (w == 1) ? wk : (w == 2) ? wv : wo;
      dst = (w == 0) ? wqb : (w == 1) ? wkb : (w == 2) ? wvb : wob;
    }
    float4 f = ((const float4*)src)[off];
    ushort4 o;
    o.x = f2bf(f.x); o.y = f2bf(f.y); o.z = f2bf(f.z); o.w = f2bf(f.w);
    ((ushort4*)dst)[off] = o;
  }
}

// ---- RoPE apply in-place on q and k [BH, T, 128] bf16 ---------------------
// q pre-scaled by (1/sqrt(128))*log2(e): flash logits are base-2.
__global__ void k_rope(unsigned short* __restrict__ q, unsigned short* __restrict__ k,
                       const float* __restrict__ ct, const float* __restrict__ st) {
  const float SC2 = 0.12751659974141322f;
  int idx = blockIdx.x * blockDim.x + threadIdx.x;
  int i = idx & 63;
  int t = (idx >> 6) & 2047;
  int bh = idx >> 17;
  size_t base = ((size_t)bh * 2048 + t) * 128;
  float c = ct[t * 64 + i], s = st[t * 64 + i];
  {
    float x1 = bf2f(q[base + i]), x2 = bf2f(q[base + i + 64]);
    q[base + i]      = f2bf((x1 * c - x2 * s) * SC2);
    q[base + i + 64] = f2bf((x2 * c + x1 * s) * SC2);
  }
  {
    float x1 = bf2f(k[base + i]), x2 = bf2f(k[base + i + 64]);
    k[base + i]      = f2bf(x1 * c - x2 * s);
    k[base + i + 64] = f2bf(x2 * c + x1 * s);
  }
}

// ---- 256x128 8-phase GEMM (verified r20: QKV 3 even rounds, Wo 1 round) ----
template <int MODE>
__global__ __launch_bounds__(512, 2) void k_gemm256n128(
    const unsigned short* __restrict__ Ag,
    const unsigned short* __restrict__ B0,
    const unsigned short* __restrict__ B1,
    const unsigned short* __restrict__ B2,
    float* __restrict__ outF,
    unsigned short* __restrict__ outQ,
    unsigned short* __restrict__ outK,
    unsigned short* __restrict__ outVT) {
  // ush: A dbuf [2][16384] @0 | B dbuf [2][8192] @32768   (= 96 KiB)
  __shared__ __align__(16) unsigned short lds[49152];

  const int tid = threadIdx.x;
  const int wid = tid >> 6, lane = tid & 63;
  const int wm = wid >> 1, wn = wid & 1;      // 4M x 2N wave grid
  const int rowA = lane & 15, kg = lane >> 4;
  const int rgrp = kg * 4;
  const int swz = rowA & 7;

  const int m0 = blockIdx.y * 256;
  const int n0g = blockIdx.x * 128;
  int w, n0;
  const unsigned short* Bg;
  if (MODE == 0) { w = 0; n0 = n0g; Bg = B0; }
  else { w = n0g >> 11; n0 = n0g & 2047; Bg = (w == 0) ? B0 : (w == 1) ? B1 : B2; }

  const int aBase = wm * 4096 + rowA * 64;
  const int bBase = wn * 4096 + rowA * 64;
  const int ch0 = (kg ^ swz) * 8;
  const int ch1 = ((4 + kg) ^ swz) * 8;

  const int grow = wid * 8 + (lane >> 3);
  const int gch  = ((lane & 7) ^ ((lane >> 3) & 7)) * 8;
  const int sdst = wid * 512;

  auto SA = [&](int dst, int t1, int c4) {
    gload_lds16(Ag + (size_t)(m0 + c4 * 64 + grow) * 2048 + t1 * 64 + gch,
                (void*)&lds[dst * 16384 + c4 * 4096 + sdst]);
  };
  auto SB = [&](int dst, int t1, int c2) {
    gload_lds16(Bg + (size_t)(n0 + c2 * 64 + grow) * 2048 + t1 * 64 + gch,
                (void*)&lds[32768 + dst * 8192 + c2 * 4096 + sdst]);
  };

  f32x4 acc[4][4];
  const f32x4 z4 = {0.f, 0.f, 0.f, 0.f};
#pragma unroll
  for (int i = 0; i < 4; ++i)
#pragma unroll
    for (int j = 0; j < 4; ++j) acc[i][j] = z4;

  SA(0, 0, 0); SA(0, 0, 1); SA(0, 0, 2); SA(0, 0, 3);
  SB(0, 0, 0); SB(0, 0, 1);
  __syncthreads();

  for (int t = 0; t < 32; ++t) {
    const int c = t & 1, d = c ^ 1;
    const int cA = c * 16384, cB = 32768 + c * 8192;
    const bool pre = (t + 1 < 32);
    const int t1 = t + 1;
    bf16x8 af[4], bk[4];

#pragma unroll
    for (int i = 0; i < 4; ++i) af[i] = *(const bf16x8*)&lds[cA + aBase + i * 1024 + ch0];
#pragma unroll
    for (int j = 0; j < 4; ++j) bk[j] = *(const bf16x8*)&lds[cB + bBase + j * 1024 + ch0];
    if (pre) { SA(d, t1, 0); SA(d, t1, 1); SB(d, t1, 0); }
    __builtin_amdgcn_s_barrier();
    __builtin_amdgcn_sched_barrier(0);
    __builtin_amdgcn_s_setprio(1);
#pragma unroll
    for (int i = 0; i < 4; ++i)
#pragma unroll
      for (int j = 0; j < 4; ++j)
        acc[i][j] = __builtin_amdgcn_mfma_f32_16x16x32_bf16(af[i], bk[j], acc[i][j], 0, 0, 0);
    __builtin_amdgcn_s_setprio(0);
    __builtin_amdgcn_s_barrier();
    __builtin_amdgcn_sched_barrier(0);

#pragma unroll
    for (int i = 0; i < 4; ++i) af[i] = *(const bf16x8*)&lds[cA + aBase + i * 1024 + ch1];
#pragma unroll
    for (int j = 0; j < 4; ++j) bk[j] = *(const bf16x8*)&lds[cB + bBase + j * 1024 + ch1];
    if (pre) { SA(d, t1, 2); SA(d, t1, 3); SB(d, t1, 1); }
    __builtin_amdgcn_s_barrier();
    __builtin_amdgcn_sched_barrier(0);
    __builtin_amdgcn_s_setprio(1);
#pragma unroll
    for (int i = 0; i < 4; ++i)
#pragma unroll
      for (int j = 0; j < 4; ++j)
        acc[i][j] = __builtin_amdgcn_mfma_f32_16x16x32_bf16(af[i], bk[j], acc[i][j], 0, 0, 0);
    __builtin_amdgcn_s_setprio(0);
    __syncthreads();
  }

#pragma unroll
  for (int i = 0; i < 4; ++i) {
#pragma unroll
    for (int j = 0; j < 4; ++j) {
      const int gm0 = m0 + wm * 64 + i * 16 + rgrp;
      const int gn  = n0 + wn * 64 + j * 16 + rowA;
      if (MODE == 0) {
#pragma unroll
        for (int r = 0; r < 4; ++r)
          outF[(size_t)(gm0 + r) * 2048 + gn] = acc[i][j][r];
      } else if (w == 2) { // transposed V
        int h = gn >> 7, dd = gn & 127;
        int b = gm0 >> 11, tt = gm0 & 2047;
        ushort4 pk;
        pk.x = f2bf(acc[i][j][0]); pk.y = f2bf(acc[i][j][1]);
        pk.z = f2bf(acc[i][j][2]); pk.w = f2bf(acc[i][j][3]);
        *(ushort4*)&outVT[(((size_t)(b * 16 + h)) * 128 + dd) * 2048 + tt] = pk;
      } else {
        unsigned short* C = w ? outK : outQ;
        int h = gn >> 7, dd = gn & 127;
        int b = gm0 >> 11, tt = gm0 & 2047;
#pragma unroll
        for (int r = 0; r < 4; ++r)
          C[(((size_t)(b * 16 + h)) * 2048 + tt + r) * 128 + dd] = f2bf(acc[i][j][r]);
      }
    }
  }
}

// ---- flash attention fwd: 512 thr = 8 waves x 16 q-rows, shared K/V stream -
// r17 skeleton (3 gates, pair-sequential (15-p,p), 17 iters, 64KB LDS with
// P overlaying K's dead space) but the 128-row q-tile splits across 8 waves
// of 16 rows instead of 4x32. Rationale: 512-thr blocks DO reach 8 waves/CU
// (r12: 20.7% occupancy) where 256-thr blocks never pass 4 (11%, r8-r19);
// the r12 failure was VGPR (~212 vs the 512-thr 128-VGPR cap) — this design
// needs only ~110 (qf[4]+s[8]+o[8] ~ 56 + addr). 2 waves/SIMD finally
// overlap the QK->softmax->PV serial chain. Per-wave 16-row math is the
// correctness-verified r18 wave code. Staging: 4 gloads/thread per tile ->
// gates become vmcnt(4)/vmcnt(0).
__global__ __launch_bounds__(512) void k_flash(const unsigned short* __restrict__ q,
                                               const unsigned short* __restrict__ k,
                                               const unsigned short* __restrict__ vt,
                                               unsigned short* __restrict__ obt) {
  // ush: K[16384] @0 (P overlays [0,8192)) | V[16384] @16384   (= 64 KiB)
  __shared__ __align__(16) unsigned short lds[32768];

  const int tid = threadIdx.x;
  const int wid = tid >> 6, lane = tid & 63;   // wid 0..7
  const int rowA = lane & 15, kg = lane >> 4;
  const int kgrp = kg * 8, rgrp = kg * 4;

  const int bid = blockIdx.x;          // 0..255
  const int xcd = bid & 7;             // round-robin XCD dispatch (perf-only)
  const int r0  = bid >> 3;            // 0..31
  const int bh  = xcd * 4 + (r0 & 3);  // 4 heads per XCD chunk
  const int p   = r0 >> 2;             // 0..7
  const int b = bh >> 4, h = bh & 15;

  const int jbs[2] = {15 - p, p};      // heavy segment first
  const int nt0 = jbs[0] + 1, nt1 = jbs[1] + 1;
  const int total = nt0 + nt1;         // = 17 for every block

  const unsigned short* qh  = q  + (size_t)bh * 2048 * 128;
  const unsigned short* kh  = k  + (size_t)bh * 2048 * 128;
  const unsigned short* vth = vt + (size_t)bh * 128 * 2048;

  // staging: call c covers rows c*32 + wid*4 + (lane>>4); 16 lanes per row.
  // dest base (c*32 + wid*4)*128 ush is wave-uniform; HW adds lane*16B which
  // equals (lane>>4)*128 + (lane&15)*8 ush — exactly row-major order.
  const int srow4 = wid * 4 + (lane >> 4); // 0..31
  auto STAGE_K = [&](int kv0) {
#pragma unroll
    for (int c = 0; c < 4; ++c) {
      int row = c * 32 + srow4;
      int ch  = (lane & 15) ^ (row & 7);
      gload_lds16(kh + (size_t)(kv0 + row) * 128 + ch * 8,
                  (void*)&lds[(c * 32 + wid * 4) * 128]);
    }
  };
  auto STAGE_V = [&](int kv0) {
#pragma unroll
    for (int c = 0; c < 4; ++c) {
      int row = c * 32 + srow4;            // d-dim row
      int ch  = (lane & 15) ^ (row & 7);
      gload_lds16(vth + (size_t)row * 2048 + kv0 + ch * 8,
                  (void*)&lds[16384 + (c * 32 + wid * 4) * 128]);
    }
  };

  const f32x4 z4 = {0.f, 0.f, 0.f, 0.f};
  bf16x8 qf[4];
  f32x4 o[8];
  float mprev[4], lsum[4];
  int q0w = 0;

  int seg = 0, it = 0;
  STAGE_K(0);   // 4 oldest vmem ops/thread
  STAGE_V(0);   // 4 newest

  for (int u = 0; u < total; ++u) {
    const int nt = (seg == 0) ? nt0 : nt1;
    const int kv0 = it * 128;

    // ---- top gate: K(u) complete everywhere; V(u) may still fly ----
    asm volatile("s_waitcnt vmcnt(4)" ::: "memory");
    __builtin_amdgcn_s_barrier();
    __builtin_amdgcn_sched_barrier(0);

    if (it == 0) {   // segment init: Q fragments (16 rows/wave) + state reset
      q0w = jbs[seg] * 128 + wid * 16;
#pragma unroll
      for (int kq = 0; kq < 4; ++kq)
        qf[kq] = *(const bf16x8*)(qh + (size_t)(q0w + rowA) * 128 + kq * 32 + kgrp);
#pragma unroll
      for (int dn = 0; dn < 8; ++dn) o[dn] = z4;
#pragma unroll
      for (int r2 = 0; r2 < 4; ++r2) { mprev[r2] = -1e30f; lsum[r2] = 0.f; }
    }

    // ---- S = Q K^T over 128 kv (swizzled LDS) ----
    f32x4 s[8];
#pragma unroll
    for (int n = 0; n < 8; ++n) s[n] = z4;
    __builtin_amdgcn_s_setprio(1);
#pragma unroll
    for (int kq = 0; kq < 4; ++kq) {
#pragma unroll
      for (int n = 0; n < 8; ++n) {
        int row = n * 16 + rowA;
        int ch  = (kq * 4 + kg) ^ (row & 7);
        bf16x8 bkk = *(const bf16x8*)&lds[row * 128 + ch * 8];
        s[n] = __builtin_amdgcn_mfma_f32_16x16x32_bf16(qf[kq], bkk, s[n], 0, 0, 0);
      }
    }
    __builtin_amdgcn_s_setprio(0);

    // ---- mid gate: V(u) drained + K reads done -> P region free, V visible
    asm volatile("s_waitcnt vmcnt(0) lgkmcnt(0)" ::: "memory");
    __builtin_amdgcn_s_barrier();
    __builtin_amdgcn_sched_barrier(0);

    // ---- causal mask (only the diagonal tile) ----
    if (kv0 + 127 > q0w) {
#pragma unroll
      for (int n = 0; n < 8; ++n)
#pragma unroll
        for (int r2 = 0; r2 < 4; ++r2) {
          int qg = q0w + rgrp + r2;
          int kgl = kv0 + n * 16 + rowA;
          if (kgl > qg) s[n][r2] = -1e30f;
        }
    }

    // ---- online softmax (base-2), step-major trees, defer-max ----
    float tmax[4];
#pragma unroll
    for (int r2 = 0; r2 < 4; ++r2) {
      float t = s[0][r2];
#pragma unroll
      for (int n = 1; n < 8; ++n) t = fmaxf(t, s[n][r2]);
      tmax[r2] = t;
    }
#pragma unroll
    for (int stp = 1; stp <= 8; stp <<= 1)
#pragma unroll
      for (int r2 = 0; r2 < 4; ++r2)
        tmax[r2] = fmaxf(tmax[r2], __shfl_xor(tmax[r2], stp));

    bool ok = true;
#pragma unroll
    for (int r2 = 0; r2 < 4; ++r2) ok = ok && (tmax[r2] <= mprev[r2] + 8.0f);
    const bool skip = __all(ok ? 1 : 0);

    float mnew[4], psum[4];
#pragma unroll
    for (int r2 = 0; r2 < 4; ++r2) {
      mnew[r2] = skip ? mprev[r2] : fmaxf(mprev[r2], tmax[r2]);
      float ps = 0.f;
#pragma unroll
      for (int n = 0; n < 8; ++n) {
        float pv = exp2f(s[n][r2] - mnew[r2]);
        s[n][r2] = pv;
        ps += pv;
      }
      psum[r2] = ps;
    }
#pragma unroll
    for (int stp = 1; stp <= 8; stp <<= 1)
#pragma unroll
      for (int r2 = 0; r2 < 4; ++r2)
        psum[r2] += __shfl_xor(psum[r2], stp);

#pragma unroll
    for (int r2 = 0; r2 < 4; ++r2) {
      if (skip) {
        lsum[r2] += psum[r2];
      } else {
        float alpha = exp2f(mprev[r2] - mnew[r2]);
        lsum[r2] = lsum[r2] * alpha + psum[r2];
        mprev[r2] = mnew[r2];
#pragma unroll
        for (int dn = 0; dn < 8; ++dn) o[dn][r2] *= alpha;
      }
    }

    // ---- PV in two passes; P [16][64]/wave overlays Kbuf[0..8192 ush) ----
    unsigned short* Pw = &lds[wid * 1024];
    const unsigned short* Vb = &lds[16384];
#pragma unroll
    for (int pass = 0; pass < 2; ++pass) {
#pragma unroll
      for (int nl = 0; nl < 4; ++nl)
#pragma unroll
        for (int r2 = 0; r2 < 4; ++r2) {
          int row = rgrp + r2;
          int col = nl * 16 + rowA;
          Pw[row * 64 + (col ^ ((row & 7) << 3))] = f2bf(s[pass * 4 + nl][r2]);
        }
      // per-wave DS ordering: compiler inserts lgkmcnt waits before reads
      __builtin_amdgcn_s_setprio(1);
#pragma unroll
      for (int kkl = 0; kkl < 2; ++kkl) {
        const int kk = pass * 2 + kkl;
        bf16x8 pa;
        {
          int row = rowA;
          int col0 = kkl * 32 + kgrp;
          pa = *(const bf16x8*)&Pw[row * 64 + (col0 ^ ((row & 7) << 3))];
        }
#pragma unroll
        for (int dn = 0; dn < 8; ++dn) {
          int row = dn * 16 + rowA;
          int ch  = (kk * 4 + kg) ^ (row & 7);
          bf16x8 vb = *(const bf16x8*)&Vb[row * 128 + ch * 8];
          o[dn] = __builtin_amdgcn_mfma_f32_16x16x32_bf16(pa, vb, o[dn], 0, 0, 0);
        }
      }
      __builtin_amdgcn_s_setprio(0);
    }

    // ---- segment epilogue: normalize and write ----
    if (it == nt - 1) {
      float rinv[4];
#pragma unroll
      for (int r2 = 0; r2 < 4; ++r2) rinv[r2] = 1.0f / lsum[r2];
#pragma unroll
      for (int dn = 0; dn < 8; ++dn)
#pragma unroll
        for (int r2 = 0; r2 < 4; ++r2) {
          float v = o[dn][r2] * rinv[r2];
          int t = q0w + rgrp + r2;
          int col = h * 128 + dn * 16 + rowA;
          obt[((size_t)b * 2048 + t) * 2048 + col] = f2bf(v);
        }
    }

    __syncthreads(); // drains everything (vmcnt0+lgkmcnt0); buffers reusable

    // ---- stage next K and V (K first = oldest; gated at next top) ----
    if (u + 1 < total) {
      const int itn = (u + 1 >= nt0) ? (u + 1 - nt0) : (u + 1);
      STAGE_K(itn * 128);
      STAGE_V(itn * 128);
    }

    ++it;
    if (seg == 0 && it == nt0) { seg = 1; it = 0; }
  }
}

// ---- host launch -----------------------------------------------------------
extern "C" void kernel_launch(void* const* d_in, const int* in_sizes, int n_in,
                              void* d_out, int out_size, void* d_ws, size_t ws_size,
                              hipStream_t stream) {
  const float* x  = (const float*)d_in[0];
  const float* Wq = (const float*)d_in[2];
  const float* Wk = (const float*)d_in[3];
  const float* Wv = (const float*)d_in[4];
  const float* Wo = (const float*)d_in[5];
  float* out = (float*)d_out;

  char* ws = (char*)d_ws;
  unsigned short* xb  = (unsigned short*)(ws + 0);
  unsigned short* wqb = (unsigned short*)(ws + 16777216);
  unsigned short* wkb = (unsigned short*)(ws + 25165824);
  unsigned short* wvb = (unsigned short*)(ws + 33554432);
  unsigned short* wob = (unsigned short*)(ws + 41943040);
  unsigned short* qb  = (unsigned short*)(ws + 50331648);
  unsigned short* kb  = (unsigned short*)(ws + 67108864);
  unsigned short* vtb = (unsigned short*)(ws + 83886080);
  unsigned short* obt = (unsigned short*)(ws + 100663296);
  float* ct = (float*)(ws + 117440512);
  float* st = (float*)(ws + 117964800);

  k_cvt5<<<2048, 256, 0, stream>>>(x, Wq, Wk, Wv, Wo, xb, wqb, wkb, wvb, wob, ct, st);
  dim3 gq(48, 16); // merged QKV: 768 blocks = 3 even rounds
  k_gemm256n128<1><<<gq, 512, 0, stream>>>(xb, wqb, wkb, wvb, nullptr, qb, kb, vtb);
  k_rope<<<16384, 256, 0, stream>>>(qb, kb, ct, st);
  k_flash<<<256, 512, 0, stream>>>(qb, kb, vtb, obt);
  dim3 go(16, 16); // Wo: 256 blocks = 1 full-chip round
  k_gemm256n128<0><<<go, 512, 0, stream>>>(obt, wob, nullptr, nullptr, out, nullptr, nullptr, nullptr);
}